// Round 15
// baseline (439.020 us; speedup 1.0000x reference)
//
#include <hip/hip_runtime.h>
#include <hip/hip_bf16.h>
#include <math.h>

#define BB 4
#define TT 2048
#define CC 256
#define HH 4
#define LL 2
#define VV 1024
#define HS 64
#define EPAD 2176
#define LOG2E 1.4426950408889634f

typedef __attribute__((ext_vector_type(8))) __bf16 bf16x8;
typedef __attribute__((ext_vector_type(4))) float f32x4;

#define MFMA16(a, b, c) __builtin_amdgcn_mfma_f32_16x16x32_bf16((a), (b), (c), 0, 0, 0)

__device__ __forceinline__ ushort f2bf(float f) {
    __hip_bfloat16 h = __float2bfloat16(f);
    return *reinterpret_cast<ushort*>(&h);
}
__device__ __forceinline__ float bf2f(ushort u) {
    union { uint i; float f; } c; c.i = ((uint)u) << 16; return c.f;
}

__device__ __forceinline__ void gload16(const void* g, void* l) {
    __builtin_amdgcn_global_load_lds(
        (const __attribute__((address_space(1))) void*)g,
        (__attribute__((address_space(3))) void*)l, 16, 0, 0);
}

__device__ __forceinline__ float gelu_f(float v) {
    return 0.5f * v * (1.0f + tanhf(0.7978845608028654f * (v + 0.044715f * v * v * v)));
}

// ---------------------------------------------------------------------------
// prep: weight cvt (blocks 0..1791) + emb band cvt (blocks 1792..2879)
// ---------------------------------------------------------------------------
__global__ void prep_kernel(const float* __restrict__ w0, const float* __restrict__ w1,
                            const float* __restrict__ w2, const float* __restrict__ w3,
                            const float* __restrict__ w4,
                            ushort* __restrict__ o0, ushort* __restrict__ o1,
                            ushort* __restrict__ o2, ushort* __restrict__ o3,
                            ushort* __restrict__ o4,
                            const float* __restrict__ ek, const float* __restrict__ ev,
                            ushort* __restrict__ ekp, ushort* __restrict__ evtp) {
    int bi = blockIdx.x;
    if (bi < 1792) {
        int i = bi * 256 + threadIdx.x;
        const float* src; ushort* dst; int j;
        if (i < 98304)       { src = w0; dst = o0; j = i; }
        else if (i < 131072) { src = w1; dst = o1; j = i - 98304; }
        else if (i < 262144) { src = w2; dst = o2; j = i - 131072; }
        else if (i < 393216) { src = w3; dst = o3; j = i - 262144; }
        else                 { src = w4; dst = o4; j = i - 393216; }
        float4 v = ((const float4*)src)[j];
        ushort4 o;
        o.x = f2bf(v.x); o.y = f2bf(v.y); o.z = f2bf(v.z); o.w = f2bf(v.w);
        ((ushort4*)dst)[j] = o;
    } else {
        int i = (bi - 1792) * 256 + threadIdx.x;   // over LL*EPAD*64
        int l = i / (EPAD * 64);
        int j = i - l * (EPAD * 64);
        int rp = j >> 6, d = j & 63;
        int o = rp - 64;
        bool in = (o >= 0 && o < TT);
        float kv = in ? ek[(size_t)l * TT * HS + (size_t)o * 64 + d] * LOG2E : 0.0f;
        float vv = in ? ev[(size_t)l * TT * HS + (size_t)o * 64 + d] : 0.0f;
        ekp[(size_t)l * EPAD * 64 + (size_t)rp * 64 + d] = f2bf(kv);
        evtp[(size_t)l * 64 * EPAD + (size_t)d * EPAD + rp] = f2bf(vv);
    }
}

// ---------------------------------------------------------------------------
// embed + ln1[0] fused: x = wte[tok], h = LN(x). One wave per row.
// ---------------------------------------------------------------------------
__global__ __launch_bounds__(256) void embed_ln_kernel(
        const int* __restrict__ tok, const float* __restrict__ wte,
        const float* __restrict__ g, const float* __restrict__ b,
        float* __restrict__ x, ushort* __restrict__ h) {
    int row = blockIdx.x * 4 + (threadIdx.x >> 6);
    int lane = threadIdx.x & 63;
    int tk = tok[row];
    float4 v = ((const float4*)(wte + (size_t)tk * CC))[lane];
    float s = v.x + v.y + v.z + v.w;
    float s2 = v.x * v.x + v.y * v.y + v.z * v.z + v.w * v.w;
    for (int m = 1; m < 64; m <<= 1) {
        s += __shfl_xor(s, m);
        s2 += __shfl_xor(s2, m);
    }
    float mean = s * (1.0f / CC);
    float var = s2 * (1.0f / CC) - mean * mean;
    float rs = rsqrtf(var + 1e-5f);
    float4 gg = ((const float4*)g)[lane];
    float4 bb = ((const float4*)b)[lane];
    ushort4 o;
    o.x = f2bf((v.x - mean) * rs * gg.x + bb.x);
    o.y = f2bf((v.y - mean) * rs * gg.y + bb.y);
    o.z = f2bf((v.z - mean) * rs * gg.z + bb.z);
    o.w = f2bf((v.w - mean) * rs * gg.w + bb.w);
    ((float4*)(x + (size_t)row * CC))[lane] = v;
    ((ushort4*)(h + (size_t)row * CC))[lane] = o;
}

// ---------------------------------------------------------------------------
// bf16 MFMA GEMM, BM=128 x BN=128, BK=32, 8 waves (2x4).
// TRIPLE-buffered LDS + counted vmcnt (kept from R13).
// MODE: 0=store f32, 2=gelu->bf16, 3=qkv split->bf16
// ---------------------------------------------------------------------------
template<int MODE>
__global__ __launch_bounds__(512) void bgemm256_kernel(
        const ushort* __restrict__ A, const ushort* __restrict__ W,
        const float* __restrict__ bias, float* __restrict__ out,
        ushort* __restrict__ outb, int N, int K,
        ushort* __restrict__ qb, ushort* __restrict__ kb,
        ushort* __restrict__ vtb) {
    constexpr int BUFSH = 16 * 512;           // 8192 ushorts = 16 KB per buf
    __shared__ ushort lds[3 * BUFSH];         // 48 KB
    int tid = threadIdx.x;
    int w = tid >> 6, lane = tid & 63;
    int lo = lane & 15, hi = lane >> 4;
    int row0 = blockIdx.y * 128;
    int col0 = blockIdx.x * 128;
    int wm = w >> 2, wn = w & 3;
    const ushort* Asrc = A + (size_t)row0 * K;
    const ushort* Wsrc = W + (size_t)col0 * K;

    auto STAGE = [&](int buf, int k0) {       // 2 loads per wave
        ushort* dst = &lds[buf * BUFSH];
        gload16(Asrc + (size_t)(w * 16 + lo) * K + k0 + hi * 8, dst + w * 512);
        gload16(Wsrc + (size_t)(w * 16 + lo) * K + k0 + hi * 8, dst + (8 + w) * 512);
    };

    f32x4 acc[4][2] = {};
    int NT = K >> 5;
    STAGE(0, 0);
    STAGE(1, 32);
    int cur = 0;
    for (int t = 0; t < NT; ++t) {
        if (t + 1 < NT) asm volatile("s_waitcnt vmcnt(2)" ::: "memory");
        else            asm volatile("s_waitcnt vmcnt(0)" ::: "memory");
        __syncthreads();
        if (t + 2 < NT) {
            int st = cur ? cur - 1 : 2;       // (t+2)%3
            STAGE(st, (t + 2) << 5);
        }
        bf16x8 a[4], b[2];
#pragma unroll
        for (int f = 0; f < 4; ++f)
            a[f] = *(const bf16x8*)&lds[cur * BUFSH + (wm * 4 + f) * 512 + lane * 8];
#pragma unroll
        for (int g = 0; g < 2; ++g)
            b[g] = *(const bf16x8*)&lds[cur * BUFSH + (8 + wn * 2 + g) * 512 + lane * 8];
        __builtin_amdgcn_s_setprio(1);
#pragma unroll
        for (int f = 0; f < 4; ++f)
#pragma unroll
            for (int g = 0; g < 2; ++g)
                acc[f][g] = MFMA16(a[f], b[g], acc[f][g]);
        __builtin_amdgcn_s_setprio(0);
        cur = cur < 2 ? cur + 1 : 0;
    }
#pragma unroll
    for (int f = 0; f < 4; ++f) {
        int rr = row0 + wm * 64 + f * 16 + hi * 4;
#pragma unroll
        for (int g = 0; g < 2; ++g) {
            int cc = col0 + wn * 32 + g * 16 + lo;
            float bv = bias ? bias[cc] : 0.0f;
#pragma unroll
            for (int j = 0; j < 4; ++j) {
                int r = rr + j;
                float v = acc[f][g][j] + bv;
                if (MODE == 3) {
                    int t = r & 2047, bb2 = r >> 11;
                    int which = cc >> 8, hh = (cc >> 6) & 3, dd = cc & 63;
                    size_t bh = (size_t)(bb2 * 4 + hh);
                    if (which == 0)      qb[(bh * 2048 + t) * 64 + dd] = f2bf(v);
                    else if (which == 1) kb[(bh * 2048 + t) * 64 + dd] = f2bf(v * (0.125f * LOG2E));
                    else                 vtb[(bh * 64 + dd) * 2048 + t] = f2bf(v);
                } else if (MODE == 2) {
                    outb[(size_t)r * N + cc] = f2bf(gelu_f(v));
                } else {
                    out[(size_t)r * N + cc] = v;
                }
            }
        }
    }
}

// ---------------------------------------------------------------------------
// Fused accumulate-GEMM + residual + LayerNorm (kept from R13).
// ---------------------------------------------------------------------------
template<int NSTEP>
__global__ __launch_bounds__(512) void bgemmln_kernel(
        const ushort* __restrict__ A, const ushort* __restrict__ W,
        const float* __restrict__ bias, float* __restrict__ x,
        const float* __restrict__ lng, const float* __restrict__ lnb,
        ushort* __restrict__ hout) {
    extern __shared__ ushort plds[];
    constexpr int K = NSTEP * 64;
    constexpr int BUFSH = 36 * 512;          // 18432 ushorts = 36 KB per buf
    int tid = threadIdx.x;
    int w = tid >> 6, lane = tid & 63;
    int lo = lane & 15, hi = lane >> 4;
    int row0 = blockIdx.x * 32;
    int wm = w >> 2, wn = w & 3;
    const ushort* Asrc = A + (size_t)row0 * K;

    auto STAGE = [&](int buf, int k0) {
        ushort* dst = &plds[buf * BUFSH];
        for (int s = w; s < 36; s += 8) {
            const ushort* src;
            if (s < 4) {
                int rg = s >> 1, kh = s & 1;
                src = Asrc + (size_t)(rg * 16 + lo) * K + k0 + kh * 32 + hi * 8;
            } else {
                int sb = s - 4, cg = sb >> 1, kh = sb & 1;
                src = W + (size_t)(cg * 16 + lo) * K + k0 + kh * 32 + hi * 8;
            }
            gload16(src, dst + s * 512);
        }
    };

    f32x4 acc[4] = {};
    STAGE(0, 0);
    STAGE(1, 64);
    int cur = 0;
    for (int t = 0; t < NSTEP; ++t) {
        if (t + 1 < NSTEP) {
            if (w < 4) asm volatile("s_waitcnt vmcnt(5)" ::: "memory");
            else       asm volatile("s_waitcnt vmcnt(4)" ::: "memory");
        } else {
            asm volatile("s_waitcnt vmcnt(0)" ::: "memory");
        }
        __syncthreads();
        if (t + 2 < NSTEP) {
            int st = cur ? cur - 1 : 2;       // (t+2)%3
            STAGE(st, (t + 2) << 6);
        }
        bf16x8 a[2];
#pragma unroll
        for (int kh = 0; kh < 2; ++kh)
            a[kh] = *(const bf16x8*)&plds[cur * BUFSH + (wm * 2 + kh) * 512 + lane * 8];
        __builtin_amdgcn_s_setprio(1);
#pragma unroll
        for (int g2 = 0; g2 < 4; ++g2) {
#pragma unroll
            for (int kh = 0; kh < 2; ++kh) {
                bf16x8 b = *(const bf16x8*)&plds[cur * BUFSH + 2048 +
                                                 ((wn * 4 + g2) * 2 + kh) * 512 + lane * 8];
                acc[g2] = MFMA16(a[kh], b, acc[g2]);
            }
        }
        __builtin_amdgcn_s_setprio(0);
        cur = cur < 2 ? cur + 1 : 0;
    }

    // ---- epilogue: v = acc + bias + x; row LN over 256 cols; write x, h ----
    float* part = (float*)&plds[3 * BUFSH];   // [2][32][4] floats (1 KB)
    float v[4][4];
    float s1[4] = {0, 0, 0, 0}, s2[4] = {0, 0, 0, 0};
#pragma unroll
    for (int g2 = 0; g2 < 4; ++g2) {
        int cc = wn * 64 + g2 * 16 + lo;
        float bv = bias[cc];
#pragma unroll
        for (int j = 0; j < 4; ++j) {
            int r = row0 + wm * 16 + hi * 4 + j;
            float tv = acc[g2][j] + bv + x[(size_t)r * CC + cc];
            v[g2][j] = tv;
            s1[j] += tv;
            s2[j] += tv * tv;
        }
    }
#pragma unroll
    for (int msk = 1; msk < 16; msk <<= 1)
#pragma unroll
        for (int j = 0; j < 4; ++j) {
            s1[j] += __shfl_xor(s1[j], msk);
            s2[j] += __shfl_xor(s2[j], msk);
        }
    if (lo == 0) {
#pragma unroll
        for (int j = 0; j < 4; ++j) {
            int rr = wm * 16 + hi * 4 + j;
            part[rr * 4 + wn] = s1[j];
            part[128 + rr * 4 + wn] = s2[j];
        }
    }
    __syncthreads();
#pragma unroll
    for (int j = 0; j < 4; ++j) {
        int rr = wm * 16 + hi * 4 + j;
        int r = row0 + rr;
        float4 p1 = *(float4*)&part[rr * 4];
        float4 p2 = *(float4*)&part[128 + rr * 4];
        float mean = (p1.x + p1.y + p1.z + p1.w) * (1.0f / CC);
        float var = (p2.x + p2.y + p2.z + p2.w) * (1.0f / CC) - mean * mean;
        float rsd = rsqrtf(var + 1e-5f);
#pragma unroll
        for (int g2 = 0; g2 < 4; ++g2) {
            int cc = wn * 64 + g2 * 16 + lo;
            x[(size_t)r * CC + cc] = v[g2][j];
            hout[(size_t)r * CC + cc] =
                f2bf((v[g2][j] - mean) * rsd * lng[cc] + lnb[cc]);
        }
    }
}

// ---------------------------------------------------------------------------
// Flash attention v3: 512 single-tile blocks (2 blocks/CU -> 4 waves/SIMD).
// K/V staged via global_load_lds (double-buffered, 32 KB); EK/EV band reads
// DIRECT from L2 (278 KB/layer, XCD-resident). Wave scratch 8 x 6 KB.
// Total dynamic LDS 80 KB. Heavy/light tiles co-located per CU via the
// double-round-robin identity (blocks g and g+256 share a CU): block g<256
// gets tile 31-pk, block g+256 gets tile pk -> 33 chunks per CU.
// Fixed-point softmax (m==0) as before.
// ---------------------------------------------------------------------------
#define FKOFF 0
#define FVOFF 8192
#define FSTG 16384
#define FWSCR 32768

__global__ __launch_bounds__(512, 4) void flash_kernel(
        const ushort* __restrict__ qb,    // [16][2048][64]
        const ushort* __restrict__ kb,    // [16][2048][64] (pre-scaled 0.125*log2e)
        const ushort* __restrict__ vtb,   // [16][64][2048]
        const ushort* __restrict__ ekp,   // [EPAD][64]  (pre-scaled log2e)
        const ushort* __restrict__ evtp,  // [64][EPAD]
        ushort* __restrict__ y) {         // [B,T,C] bf16
    extern __shared__ __align__(16) char dls[];

    int g = blockIdx.x;
    int phase = g >> 8;                   // 0 = heavy half, 1 = light half
    int pk = (g >> 4) & 15;
    int bh = g & 15;                      // g%8 = bh%8 -> bh pinned to XCD
    int tile = phase ? pk : (31 - pk);
    int t0 = tile * 64;
    int NS = tile + 1;

    int tid = threadIdx.x;
    int w = tid >> 6;
    int sub = w & 3;
    int h = w >> 2;
    int lane = tid & 63;
    int lo = lane & 15, hi = lane >> 4;
    int sw = (lo & 7) << 4;

    char* wbase = dls + FWSCR + w * 6144;
    ushort (*Rl)[88]   = (ushort (*)[88])  wbase;
    ushort (*Pl)[72]   = (ushort (*)[72])  wbase;            // aliases Rl
    ushort (*Ppl)[104] = (ushort (*)[104])(wbase + 2816);

    {   // zero own P' halo once
        uint* pz = reinterpret_cast<uint*>(&Ppl[0][0]);
        for (int i = lane; i < 832; i += 64) pz[i] = 0;
    }

    const char* kB = (const char*)(kb + (size_t)bh * 2048 * 64);
    const char* vB = (const char*)(vtb + (size_t)bh * 64 * 2048);

    auto STAGE_KV = [&](int buf, int s0) {    // 2 loads/thread: K + V^T
        char* B = dls + buf * FSTG;
        int wb = (tid & 448) << 4;            // wave-uniform dest base
        int gb = tid * 16;
        int r = gb >> 7, c = gb & 127;
        gload16(kB + (size_t)(s0 + r) * 128 + (c ^ ((r & 7) << 4)), B + FKOFF + wb);
        gload16(vB + (size_t)r * 4096 + (size_t)s0 * 2 + (c ^ ((r & 7) << 4)),
                B + FVOFF + wb);
    };

    const ushort* qbase = qb + ((size_t)bh * 2048 + t0 + sub * 16) * 64;
    bf16x8 qf0 = *(const bf16x8*)(qbase + (size_t)lo * 64 + hi * 8);
    bf16x8 qf1 = *(const bf16x8*)(qbase + (size_t)lo * 64 + 32 + hi * 8);
    STAGE_KV(0, 0);

    int b_ = bh >> 2, h_ = bh & 3;
    int nb = h ? 0 : 2;
    int kcA = h ? 0 : 1, kcB = h ? 1 : 2;

    float rs[4] = {0.0f, 0.0f, 0.0f, 0.0f};
    f32x4 O[4] = {};

    for (int c = 0; c < NS; ++c) {
        int cur = c & 1;
        const char* B = dls + cur * FSTG;
        int s0 = c * 64;
        int band0 = t0 - s0;
        bool diag = (c == NS - 1);

        asm volatile("s_waitcnt vmcnt(0)" ::: "memory");
        __syncthreads();
        if (c + 1 < NS) STAGE_KV(cur ^ 1, s0 + 64);

        // ---- S = Q K^T (staged K) ----
        f32x4 sacc[2] = {};
        __builtin_amdgcn_s_setprio(1);
#pragma unroll
        for (int ni = 0; ni < 2; ++ni) {
            int R = (2 * h + ni) * 16 + lo;
            bf16x8 b0 = *(const bf16x8*)(B + FKOFF + R * 128 + ((hi * 16) ^ sw));
            bf16x8 b1 = *(const bf16x8*)(B + FKOFF + R * 128 + ((64 + hi * 16) ^ sw));
            sacc[ni] = MFMA16(qf0, b0, sacc[ni]);
            sacc[ni] = MFMA16(qf1, b1, sacc[ni]);
        }
        // ---- R = Q ek_band^T (EK direct from L2) -> own Rl ----
#pragma unroll
        for (int ni = 0; ni < 3; ++ni) {
            int n = nb + ni;
            int RL = (sub + n) * 16 + lo;
            const ushort* ekr = ekp + (size_t)(band0 + RL) * 64;
            bf16x8 e0 = *(const bf16x8*)(ekr + hi * 8);
            bf16x8 e1 = *(const bf16x8*)(ekr + 32 + hi * 8);
            f32x4 r = {};
            r = MFMA16(qf0, e0, r);
            r = MFMA16(qf1, e1, r);
#pragma unroll
            for (int j = 0; j < 4; ++j) Rl[hi * 4 + j][n * 16 + lo] = f2bf(r[j]);
        }
        __builtin_amdgcn_s_setprio(0);
        // ---- combine + mask + exp2 ----
        float sv[2][4];
#pragma unroll
        for (int ni = 0; ni < 2; ++ni) {
            int sl = (2 * h + ni) * 16 + lo;
#pragma unroll
            for (int j = 0; j < 4; ++j) {
                int r_ = hi * 4 + j;
                sv[ni][j] = sacc[ni][j] + bf2f(Rl[r_][r_ - sl + 64]);
            }
        }
        asm volatile("" ::: "memory");   // Rl reads before Pl writes (alias)
#pragma unroll
        for (int ni = 0; ni < 2; ++ni) {
            int sl = (2 * h + ni) * 16 + lo;
#pragma unroll
            for (int j = 0; j < 4; ++j) {
                int r_ = hi * 4 + j;
                float p = (!diag || sl <= sub * 16 + r_) ? exp2f(sv[ni][j]) : 0.0f;
                rs[j] += p;
                ushort pu = f2bf(p);
                Pl[r_][sl] = pu;
                Ppl[r_][r_ - sl + 64] = pu;
            }
        }
        asm volatile("" ::: "memory");   // P writes before P reads

        // ---- O += P V (staged V) + P' ev (EV direct from L2) ----
        __builtin_amdgcn_s_setprio(1);
        bf16x8 pa  = *(const bf16x8*)(&Pl[lo][h * 32 + hi * 8]);
        bf16x8 pb0 = *(const bf16x8*)(&Ppl[lo][kcA * 32 + hi * 8]);
        bf16x8 pb1 = *(const bf16x8*)(&Ppl[lo][kcB * 32 + hi * 8]);
#pragma unroll
        for (int n = 0; n < 4; ++n) {
            int R = n * 16 + lo;
            const ushort* evr = evtp + (size_t)R * EPAD + band0 + sub * 16;
            bf16x8 bv = *(const bf16x8*)(B + FVOFF + R * 128 + ((h * 64 + hi * 16) ^ sw));
            O[n] = MFMA16(pa, bv, O[n]);
            bf16x8 e0 = *(const bf16x8*)(evr + kcA * 32 + hi * 8);
            O[n] = MFMA16(pb0, e0, O[n]);
            bf16x8 e1 = *(const bf16x8*)(evr + kcB * 32 + hi * 8);
            O[n] = MFMA16(pb1, e1, O[n]);
        }
        __builtin_amdgcn_s_setprio(0);
        asm volatile("" ::: "memory");   // P reads before next chunk's Rl writes
    }

    // ---- 2-half merge via the (now idle) staging area ----
#pragma unroll
    for (int msk = 1; msk < 16; msk <<= 1)
#pragma unroll
        for (int j = 0; j < 4; ++j) rs[j] += __shfl_xor(rs[j], msk);

    char* mscr = dls + sub * 8192;       // 4 x 8KB inside the 32KB staging area
    __syncthreads();                     // all waves done with staged V reads
    if (h == 1) {
        float* Of = (float*)mscr;
#pragma unroll
        for (int n = 0; n < 4; ++n)
#pragma unroll
            for (int j = 0; j < 4; ++j)
                Of[(hi * 4 + j) * 64 + n * 16 + lo] = O[n][j];
        if (lo == 0)
#pragma unroll
            for (int j = 0; j < 4; ++j)
                ((float*)(mscr + 4096))[hi * 4 + j] = rs[j];
    }
    __syncthreads();
    if (h == 0) {
        float* Of = (float*)mscr;
        float inv[4];
#pragma unroll
        for (int j = 0; j < 4; ++j)
            inv[j] = 1.0f / (rs[j] + ((float*)(mscr + 4096))[hi * 4 + j]);
#pragma unroll
        for (int n = 0; n < 4; ++n)
#pragma unroll
            for (int j = 0; j < 4; ++j) {
                int r = t0 + sub * 16 + hi * 4 + j;
                float v = O[n][j] + Of[(hi * 4 + j) * 64 + n * 16 + lo];
                y[((size_t)(b_ * 2048 + r)) * 256 + h_ * 64 + n * 16 + lo] =
                    f2bf(v * inv[j]);
            }
    }
}

// ---------------------------------------------------------------------------
extern "C" void kernel_launch(void* const* d_in, const int* in_sizes, int n_in,
                              void* d_out, int out_size, void* d_ws, size_t ws_size,
                              hipStream_t stream) {
    const int*   tokens  = (const int*)d_in[0];
    const float* wte     = (const float*)d_in[1];
    const float* ln1_g   = (const float*)d_in[2];
    const float* ln1_b   = (const float*)d_in[3];
    const float* attn_w  = (const float*)d_in[4];
    const float* attn_b  = (const float*)d_in[5];
    const float* proj_w  = (const float*)d_in[6];
    const float* proj_b  = (const float*)d_in[7];
    const float* embk    = (const float*)d_in[8];
    const float* embv    = (const float*)d_in[9];
    const float* ln2_g   = (const float*)d_in[10];
    const float* ln2_b   = (const float*)d_in[11];
    const float* fc_w    = (const float*)d_in[12];
    const float* fc_b    = (const float*)d_in[13];
    const float* mproj_w = (const float*)d_in[14];
    const float* mproj_b = (const float*)d_in[15];
    const float* lnf_g   = (const float*)d_in[16];
    const float* lnf_b   = (const float*)d_in[17];
    const float* head_w  = (const float*)d_in[18];
    float* out = (float*)d_out;

    const int M = BB * TT;  // 8192
    char* wsb = (char*)d_ws;
    float*  x    = (float*)wsb;                               // 8 MB
    ushort* h    = (ushort*)(wsb + ((size_t)8 << 20));        // 4 MB
    ushort* y    = (ushort*)(wsb + ((size_t)12 << 20));       // 4 MB
    ushort* qb   = (ushort*)(wsb + ((size_t)16 << 20));       // 4 MB
    ushort* kbf  = (ushort*)(wsb + ((size_t)20 << 20));       // 4 MB
    ushort* vtb  = (ushort*)(wsb + ((size_t)24 << 20));       // 4 MB
    ushort* ekp  = (ushort*)(wsb + ((size_t)28 << 20));       // 2 x 278528 B
    ushort* evtp = ekp + (size_t)LL * EPAD * 64;              // 2 x 278528 B
    ushort* attn_wb  = (ushort*)(wsb + ((size_t)30 << 20));   // 3.7 MB total
    ushort* proj_wb  = attn_wb + (size_t)LL * 3 * CC * CC;
    ushort* fc_wb    = proj_wb + (size_t)LL * CC * CC;
    ushort* mproj_wb = fc_wb + (size_t)LL * 4 * CC * CC;
    ushort* head_wb  = mproj_wb + (size_t)LL * CC * 4 * CC;
    ushort* fcb = (ushort*)d_out;  // d_out reused as fc scratch (bf16)

    dim3 blk(256);
    const int FLDS = FWSCR + 8 * 6144;       // 81920 B -> 2 blocks/CU
    const int PLDS = 3 * 36864 + 1024;       // 111616 B
    hipFuncSetAttribute(reinterpret_cast<const void*>(flash_kernel),
                        hipFuncAttributeMaxDynamicSharedMemorySize, FLDS);
    hipFuncSetAttribute(reinterpret_cast<const void*>(bgemmln_kernel<4>),
                        hipFuncAttributeMaxDynamicSharedMemorySize, PLDS);
    hipFuncSetAttribute(reinterpret_cast<const void*>(bgemmln_kernel<16>),
                        hipFuncAttributeMaxDynamicSharedMemorySize, PLDS);

    prep_kernel<<<dim3(2880), blk, 0, stream>>>(
        attn_w, proj_w, fc_w, mproj_w, head_w,
        attn_wb, proj_wb, fc_wb, mproj_wb, head_wb,
        embk, embv, ekp, evtp);

    embed_ln_kernel<<<dim3(M / 4), blk, 0, stream>>>(
        tokens, wte, ln1_g, ln1_b, x, h);

    for (int l = 0; l < LL; l++) {
        bgemm256_kernel<3><<<dim3(6, 64), dim3(512), 0, stream>>>(
            h, attn_wb + (size_t)l * 3 * CC * CC, attn_b + (size_t)l * 3 * CC,
            nullptr, nullptr, 3 * CC, CC, qb, kbf, vtb);
        flash_kernel<<<dim3(512), dim3(512), FLDS, stream>>>(
            qb, kbf, vtb, ekp + (size_t)l * EPAD * 64, evtp + (size_t)l * 64 * EPAD, y);
        bgemmln_kernel<4><<<dim3(256), dim3(512), PLDS, stream>>>(
            y, proj_wb + (size_t)l * CC * CC, proj_b + (size_t)l * CC,
            x, ln2_g + l * CC, ln2_b + l * CC, h);
        bgemm256_kernel<2><<<dim3(8, 64), dim3(512), 0, stream>>>(
            h, fc_wb + (size_t)l * 4 * CC * CC, fc_b + (size_t)l * 4 * CC,
            nullptr, fcb, 4 * CC, CC, nullptr, nullptr, nullptr);
        const float* ng = (l == 0) ? (ln1_g + CC) : lnf_g;
        const float* nb = (l == 0) ? (ln1_b + CC) : lnf_b;
        bgemmln_kernel<16><<<dim3(256), dim3(512), PLDS, stream>>>(
            fcb, mproj_wb + (size_t)l * CC * 4 * CC, mproj_b + (size_t)l * CC,
            x, ng, nb, h);
    }

    bgemm256_kernel<0><<<dim3(8, 64), dim3(512), 0, stream>>>(
        h, head_wb, nullptr, out, nullptr, VV, CC, nullptr, nullptr, nullptr);
}

// Round 16
// 323.944 us; speedup vs baseline: 1.3552x; 1.3552x over previous
//
#include <hip/hip_runtime.h>
#include <hip/hip_bf16.h>
#include <math.h>

#define BB 4
#define TT 2048
#define CC 256
#define HH 4
#define LL 2
#define VV 1024
#define HS 64
#define EPAD 2176
#define LOG2E 1.4426950408889634f

typedef __attribute__((ext_vector_type(8))) __bf16 bf16x8;
typedef __attribute__((ext_vector_type(4))) float f32x4;

#define MFMA16(a, b, c) __builtin_amdgcn_mfma_f32_16x16x32_bf16((a), (b), (c), 0, 0, 0)

__device__ __forceinline__ ushort f2bf(float f) {
    __hip_bfloat16 h = __float2bfloat16(f);
    return *reinterpret_cast<ushort*>(&h);
}
__device__ __forceinline__ float bf2f(ushort u) {
    union { uint i; float f; } c; c.i = ((uint)u) << 16; return c.f;
}

__device__ __forceinline__ void gload16(const void* g, void* l) {
    __builtin_amdgcn_global_load_lds(
        (const __attribute__((address_space(1))) void*)g,
        (__attribute__((address_space(3))) void*)l, 16, 0, 0);
}

__device__ __forceinline__ float gelu_f(float v) {
    return 0.5f * v * (1.0f + tanhf(0.7978845608028654f * (v + 0.044715f * v * v * v)));
}

// ---------------------------------------------------------------------------
// prep: weight cvt (blocks 0..1791) + emb band cvt (blocks 1792..2879)
// ---------------------------------------------------------------------------
__global__ void prep_kernel(const float* __restrict__ w0, const float* __restrict__ w1,
                            const float* __restrict__ w2, const float* __restrict__ w3,
                            const float* __restrict__ w4,
                            ushort* __restrict__ o0, ushort* __restrict__ o1,
                            ushort* __restrict__ o2, ushort* __restrict__ o3,
                            ushort* __restrict__ o4,
                            const float* __restrict__ ek, const float* __restrict__ ev,
                            ushort* __restrict__ ekp, ushort* __restrict__ evtp) {
    int bi = blockIdx.x;
    if (bi < 1792) {
        int i = bi * 256 + threadIdx.x;
        const float* src; ushort* dst; int j;
        if (i < 98304)       { src = w0; dst = o0; j = i; }
        else if (i < 131072) { src = w1; dst = o1; j = i - 98304; }
        else if (i < 262144) { src = w2; dst = o2; j = i - 131072; }
        else if (i < 393216) { src = w3; dst = o3; j = i - 262144; }
        else                 { src = w4; dst = o4; j = i - 393216; }
        float4 v = ((const float4*)src)[j];
        ushort4 o;
        o.x = f2bf(v.x); o.y = f2bf(v.y); o.z = f2bf(v.z); o.w = f2bf(v.w);
        ((ushort4*)dst)[j] = o;
    } else {
        int i = (bi - 1792) * 256 + threadIdx.x;   // over LL*EPAD*64
        int l = i / (EPAD * 64);
        int j = i - l * (EPAD * 64);
        int rp = j >> 6, d = j & 63;
        int o = rp - 64;
        bool in = (o >= 0 && o < TT);
        float kv = in ? ek[(size_t)l * TT * HS + (size_t)o * 64 + d] * LOG2E : 0.0f;
        float vv = in ? ev[(size_t)l * TT * HS + (size_t)o * 64 + d] : 0.0f;
        ekp[(size_t)l * EPAD * 64 + (size_t)rp * 64 + d] = f2bf(kv);
        evtp[(size_t)l * 64 * EPAD + (size_t)d * EPAD + rp] = f2bf(vv);
    }
}

// ---------------------------------------------------------------------------
// embed + ln1[0] fused: x = wte[tok], h = LN(x). One wave per row.
// ---------------------------------------------------------------------------
__global__ __launch_bounds__(256) void embed_ln_kernel(
        const int* __restrict__ tok, const float* __restrict__ wte,
        const float* __restrict__ g, const float* __restrict__ b,
        float* __restrict__ x, ushort* __restrict__ h) {
    int row = blockIdx.x * 4 + (threadIdx.x >> 6);
    int lane = threadIdx.x & 63;
    int tk = tok[row];
    float4 v = ((const float4*)(wte + (size_t)tk * CC))[lane];
    float s = v.x + v.y + v.z + v.w;
    float s2 = v.x * v.x + v.y * v.y + v.z * v.z + v.w * v.w;
    for (int m = 1; m < 64; m <<= 1) {
        s += __shfl_xor(s, m);
        s2 += __shfl_xor(s2, m);
    }
    float mean = s * (1.0f / CC);
    float var = s2 * (1.0f / CC) - mean * mean;
    float rs = rsqrtf(var + 1e-5f);
    float4 gg = ((const float4*)g)[lane];
    float4 bb = ((const float4*)b)[lane];
    ushort4 o;
    o.x = f2bf((v.x - mean) * rs * gg.x + bb.x);
    o.y = f2bf((v.y - mean) * rs * gg.y + bb.y);
    o.z = f2bf((v.z - mean) * rs * gg.z + bb.z);
    o.w = f2bf((v.w - mean) * rs * gg.w + bb.w);
    ((float4*)(x + (size_t)row * CC))[lane] = v;
    ((ushort4*)(h + (size_t)row * CC))[lane] = o;
}

// ---------------------------------------------------------------------------
// bf16 MFMA GEMM, BM=128 x BN=128, BK=32, 8 waves (2x4).
// TRIPLE-buffered LDS + counted vmcnt.
// MODE: 0=store f32, 2=gelu->bf16, 3=qkv split->bf16
// ---------------------------------------------------------------------------
template<int MODE>
__global__ __launch_bounds__(512) void bgemm256_kernel(
        const ushort* __restrict__ A, const ushort* __restrict__ W,
        const float* __restrict__ bias, float* __restrict__ out,
        ushort* __restrict__ outb, int N, int K,
        ushort* __restrict__ qb, ushort* __restrict__ kb,
        ushort* __restrict__ vtb) {
    constexpr int BUFSH = 16 * 512;           // 8192 ushorts = 16 KB per buf
    __shared__ ushort lds[3 * BUFSH];         // 48 KB
    int tid = threadIdx.x;
    int w = tid >> 6, lane = tid & 63;
    int lo = lane & 15, hi = lane >> 4;
    int row0 = blockIdx.y * 128;
    int col0 = blockIdx.x * 128;
    int wm = w >> 2, wn = w & 3;
    const ushort* Asrc = A + (size_t)row0 * K;
    const ushort* Wsrc = W + (size_t)col0 * K;

    auto STAGE = [&](int buf, int k0) {       // 2 loads per wave
        ushort* dst = &lds[buf * BUFSH];
        gload16(Asrc + (size_t)(w * 16 + lo) * K + k0 + hi * 8, dst + w * 512);
        gload16(Wsrc + (size_t)(w * 16 + lo) * K + k0 + hi * 8, dst + (8 + w) * 512);
    };

    f32x4 acc[4][2] = {};
    int NT = K >> 5;
    STAGE(0, 0);
    STAGE(1, 32);
    int cur = 0;
    for (int t = 0; t < NT; ++t) {
        if (t + 1 < NT) asm volatile("s_waitcnt vmcnt(2)" ::: "memory");
        else            asm volatile("s_waitcnt vmcnt(0)" ::: "memory");
        __syncthreads();
        if (t + 2 < NT) {
            int st = cur ? cur - 1 : 2;       // (t+2)%3
            STAGE(st, (t + 2) << 5);
        }
        bf16x8 a[4], b[2];
#pragma unroll
        for (int f = 0; f < 4; ++f)
            a[f] = *(const bf16x8*)&lds[cur * BUFSH + (wm * 4 + f) * 512 + lane * 8];
#pragma unroll
        for (int g = 0; g < 2; ++g)
            b[g] = *(const bf16x8*)&lds[cur * BUFSH + (8 + wn * 2 + g) * 512 + lane * 8];
        __builtin_amdgcn_s_setprio(1);
#pragma unroll
        for (int f = 0; f < 4; ++f)
#pragma unroll
            for (int g = 0; g < 2; ++g)
                acc[f][g] = MFMA16(a[f], b[g], acc[f][g]);
        __builtin_amdgcn_s_setprio(0);
        cur = cur < 2 ? cur + 1 : 0;
    }
#pragma unroll
    for (int f = 0; f < 4; ++f) {
        int rr = row0 + wm * 64 + f * 16 + hi * 4;
#pragma unroll
        for (int g = 0; g < 2; ++g) {
            int cc = col0 + wn * 32 + g * 16 + lo;
            float bv = bias ? bias[cc] : 0.0f;
#pragma unroll
            for (int j = 0; j < 4; ++j) {
                int r = rr + j;
                float v = acc[f][g][j] + bv;
                if (MODE == 3) {
                    int t = r & 2047, bb2 = r >> 11;
                    int which = cc >> 8, hh = (cc >> 6) & 3, dd = cc & 63;
                    size_t bh = (size_t)(bb2 * 4 + hh);
                    if (which == 0)      qb[(bh * 2048 + t) * 64 + dd] = f2bf(v);
                    else if (which == 1) kb[(bh * 2048 + t) * 64 + dd] = f2bf(v * (0.125f * LOG2E));
                    else                 vtb[(bh * 64 + dd) * 2048 + t] = f2bf(v);
                } else if (MODE == 2) {
                    outb[(size_t)r * N + cc] = f2bf(gelu_f(v));
                } else {
                    out[(size_t)r * N + cc] = v;
                }
            }
        }
    }
}

// ---------------------------------------------------------------------------
// Fused accumulate-GEMM + residual + LayerNorm. BM=32, BN=256 (full width),
// BK=64, 8 waves (2x4). TRIPLE-buffered counted-vmcnt pipeline.
// out: x (f32, residual updated) and h = LN(x) (bf16).  K = NSTEP*64.
// ---------------------------------------------------------------------------
template<int NSTEP>
__global__ __launch_bounds__(512) void bgemmln_kernel(
        const ushort* __restrict__ A, const ushort* __restrict__ W,
        const float* __restrict__ bias, float* __restrict__ x,
        const float* __restrict__ lng, const float* __restrict__ lnb,
        ushort* __restrict__ hout) {
    extern __shared__ ushort plds[];
    constexpr int K = NSTEP * 64;
    constexpr int BUFSH = 36 * 512;          // 18432 ushorts = 36 KB per buf
    int tid = threadIdx.x;
    int w = tid >> 6, lane = tid & 63;
    int lo = lane & 15, hi = lane >> 4;
    int row0 = blockIdx.x * 32;
    int wm = w >> 2, wn = w & 3;
    const ushort* Asrc = A + (size_t)row0 * K;

    auto STAGE = [&](int buf, int k0) {
        ushort* dst = &plds[buf * BUFSH];
        for (int s = w; s < 36; s += 8) {
            const ushort* src;
            if (s < 4) {
                int rg = s >> 1, kh = s & 1;
                src = Asrc + (size_t)(rg * 16 + lo) * K + k0 + kh * 32 + hi * 8;
            } else {
                int sb = s - 4, cg = sb >> 1, kh = sb & 1;
                src = W + (size_t)(cg * 16 + lo) * K + k0 + kh * 32 + hi * 8;
            }
            gload16(src, dst + s * 512);
        }
    };

    f32x4 acc[4] = {};
    STAGE(0, 0);
    STAGE(1, 64);
    int cur = 0;
    for (int t = 0; t < NSTEP; ++t) {
        if (t + 1 < NSTEP) {
            if (w < 4) asm volatile("s_waitcnt vmcnt(5)" ::: "memory");
            else       asm volatile("s_waitcnt vmcnt(4)" ::: "memory");
        } else {
            asm volatile("s_waitcnt vmcnt(0)" ::: "memory");
        }
        __syncthreads();
        if (t + 2 < NSTEP) {
            int st = cur ? cur - 1 : 2;       // (t+2)%3
            STAGE(st, (t + 2) << 6);
        }
        bf16x8 a[2];
#pragma unroll
        for (int kh = 0; kh < 2; ++kh)
            a[kh] = *(const bf16x8*)&plds[cur * BUFSH + (wm * 2 + kh) * 512 + lane * 8];
        __builtin_amdgcn_s_setprio(1);
#pragma unroll
        for (int g2 = 0; g2 < 4; ++g2) {
#pragma unroll
            for (int kh = 0; kh < 2; ++kh) {
                bf16x8 b = *(const bf16x8*)&plds[cur * BUFSH + 2048 +
                                                 ((wn * 4 + g2) * 2 + kh) * 512 + lane * 8];
                acc[g2] = MFMA16(a[kh], b, acc[g2]);
            }
        }
        __builtin_amdgcn_s_setprio(0);
        cur = cur < 2 ? cur + 1 : 0;
    }

    // ---- epilogue: v = acc + bias + x; row LN over 256 cols; write x, h ----
    float* part = (float*)&plds[3 * BUFSH];   // [2][32][4] floats (1 KB)
    float v[4][4];
    float s1[4] = {0, 0, 0, 0}, s2[4] = {0, 0, 0, 0};
#pragma unroll
    for (int g2 = 0; g2 < 4; ++g2) {
        int cc = wn * 64 + g2 * 16 + lo;
        float bv = bias[cc];
#pragma unroll
        for (int j = 0; j < 4; ++j) {
            int r = row0 + wm * 16 + hi * 4 + j;
            float tv = acc[g2][j] + bv + x[(size_t)r * CC + cc];
            v[g2][j] = tv;
            s1[j] += tv;
            s2[j] += tv * tv;
        }
    }
#pragma unroll
    for (int msk = 1; msk < 16; msk <<= 1)
#pragma unroll
        for (int j = 0; j < 4; ++j) {
            s1[j] += __shfl_xor(s1[j], msk);
            s2[j] += __shfl_xor(s2[j], msk);
        }
    if (lo == 0) {
#pragma unroll
        for (int j = 0; j < 4; ++j) {
            int rr = wm * 16 + hi * 4 + j;
            part[rr * 4 + wn] = s1[j];
            part[128 + rr * 4 + wn] = s2[j];
        }
    }
    __syncthreads();
#pragma unroll
    for (int j = 0; j < 4; ++j) {
        int rr = wm * 16 + hi * 4 + j;
        int r = row0 + rr;
        float4 p1 = *(float4*)&part[rr * 4];
        float4 p2 = *(float4*)&part[128 + rr * 4];
        float mean = (p1.x + p1.y + p1.z + p1.w) * (1.0f / CC);
        float var = (p2.x + p2.y + p2.z + p2.w) * (1.0f / CC) - mean * mean;
        float rsd = rsqrtf(var + 1e-5f);
#pragma unroll
        for (int g2 = 0; g2 < 4; ++g2) {
            int cc = wn * 64 + g2 * 16 + lo;
            x[(size_t)r * CC + cc] = v[g2][j];
            hout[(size_t)r * CC + cc] =
                f2bf((v[g2][j] - mean) * rsd * lng[cc] + lnb[cc]);
        }
    }
}

// ---------------------------------------------------------------------------
// Cooperative staged flash attention, 8 waves, fixed-point softmax.
// Per-chunk TWO-PHASE counted-vmcnt schedule (R14 — best measured).
// ---------------------------------------------------------------------------
#define SBUF 57344
#define KOFF 0
#define VOFF 8192
#define EKOFF 16384
#define EVOFF 32768
#define WSCR (2 * SBUF)

__global__ __launch_bounds__(512, 2) void flash_kernel(
        const ushort* __restrict__ qb,    // [16][2048][64]
        const ushort* __restrict__ kb,    // [16][2048][64] (pre-scaled 0.125*log2e)
        const ushort* __restrict__ vtb,   // [16][64][2048]
        const ushort* __restrict__ ekp,   // [EPAD][64]  (pre-scaled log2e)
        const ushort* __restrict__ evtp,  // [64][EPAD]
        ushort* __restrict__ y) {         // [B,T,C] bf16
    extern __shared__ __align__(16) char dls[];

    int g = blockIdx.x;
    int lbid = ((g & 7) << 5) | (g >> 3);
    int bh = lbid >> 4;
    int pk = lbid & 15;
    int tid = threadIdx.x;
    int w = tid >> 6;
    int sub = w & 3;
    int h = w >> 2;
    int lane = tid & 63;
    int lo = lane & 15, hi = lane >> 4;
    int sw = (lo & 7) << 4;

    char* wbase = dls + WSCR + w * 6144;
    ushort (*Rl)[88]   = (ushort (*)[88])  wbase;
    ushort (*Pl)[72]   = (ushort (*)[72])  wbase;
    ushort (*Ppl)[104] = (ushort (*)[104])(wbase + 2816);

    {
        uint* pz = reinterpret_cast<uint*>(&Ppl[0][0]);
        for (int i = lane; i < 832; i += 64) pz[i] = 0;
    }

    const char* kB  = (const char*)(kb  + (size_t)bh * 2048 * 64);
    const char* vB  = (const char*)(vtb + (size_t)bh * 64 * 2048);
    const char* ekB = (const char*)ekp;
    const char* evB = (const char*)evtp;

    int t0A = (31 - pk) * 64, t0B = pk * 64;
    int NSA = 32 - pk;
    const int NC = 33;

    auto STAGE_KE = [&](int buf, int ci) {    // 3 loads/thread: K + EK band
        int t0 = (ci < NSA) ? t0A : t0B;
        int s0 = ((ci < NSA) ? ci : ci - NSA) * 64;
        int band0 = t0 - s0;
        char* B = dls + buf * SBUF;
        int wb = (tid & 448) << 4;
        {
            int gb = tid * 16;
            int r = gb >> 7, c = gb & 127;
            gload16(kB + (size_t)(s0 + r) * 128 + (c ^ ((r & 7) << 4)), B + KOFF + wb);
        }
#pragma unroll
        for (int p = 0; p < 2; ++p) {
            int gb = p * 8192 + tid * 16;
            int r = gb >> 7, c = gb & 127;
            gload16(ekB + (size_t)(band0 + r) * 128 + (c ^ ((r & 7) << 4)),
                    B + EKOFF + p * 8192 + wb);
        }
    };
    auto STAGE_VE = [&](int buf, int ci) {    // 4 loads/thread: V + EV band
        int t0 = (ci < NSA) ? t0A : t0B;
        int s0 = ((ci < NSA) ? ci : ci - NSA) * 64;
        int band0 = t0 - s0;
        char* B = dls + buf * SBUF;
        int wb = (tid & 448) << 4;
        {
            int gb = tid * 16;
            int r = gb >> 7, c = gb & 127;
            gload16(vB + (size_t)r * 4096 + (size_t)s0 * 2 + (c ^ ((r & 7) << 4)),
                    B + VOFF + wb);
        }
#pragma unroll
        for (int p = 0; p < 3; ++p) {
            int gb = p * 8192 + tid * 16;
            int r = gb / 384, c = gb - r * 384;
            gload16(evB + (size_t)r * 4352 + (size_t)band0 * 2 + (c ^ ((r & 7) << 4)),
                    B + EVOFF + p * 8192 + wb);
        }
    };

    // prologue: Q fragments for both tiles FIRST (oldest in vmcnt order),
    // then chunk 0's stage.
    const ushort* qbaseA = qb + ((size_t)bh * 2048 + t0A + sub * 16) * 64;
    const ushort* qbaseB = qb + ((size_t)bh * 2048 + t0B + sub * 16) * 64;
    bf16x8 qfA0 = *(const bf16x8*)(qbaseA + (size_t)lo * 64 + hi * 8);
    bf16x8 qfA1 = *(const bf16x8*)(qbaseA + (size_t)lo * 64 + 32 + hi * 8);
    bf16x8 qfB0 = *(const bf16x8*)(qbaseB + (size_t)lo * 64 + hi * 8);
    bf16x8 qfB1 = *(const bf16x8*)(qbaseB + (size_t)lo * 64 + 32 + hi * 8);
    STAGE_KE(0, 0);
    STAGE_VE(0, 0);

    int b_ = bh >> 2, h_ = bh & 3;
    int ci = 0;
    int nb = h ? 0 : 2;
    int kcA = h ? 0 : 1, kcB = h ? 1 : 2;

    for (int tile = 0; tile < 2; ++tile) {
        int t0 = tile ? t0B : t0A;
        int NS = tile ? (pk + 1) : NSA;
        bf16x8 qf0 = tile ? qfB0 : qfA0;
        bf16x8 qf1 = tile ? qfB1 : qfA1;

        float rs[4] = {0.0f, 0.0f, 0.0f, 0.0f};
        f32x4 O[4] = {};

        for (int c = 0; c < NS; ++c, ++ci) {
            int cur = ci & 1;
            const char* B = dls + cur * SBUF;
            bool diag = (c == NS - 1);

            // ---- phase A gate: K/EK of cur landed; V/EV still in flight ----
            asm volatile("s_waitcnt vmcnt(4)" ::: "memory");
            __syncthreads();
            if (ci + 1 < NC) STAGE_KE(cur ^ 1, ci + 1);

            // ---- S = Q K^T ----
            f32x4 sacc[2] = {};
            __builtin_amdgcn_s_setprio(1);
#pragma unroll
            for (int ni = 0; ni < 2; ++ni) {
                int R = (2 * h + ni) * 16 + lo;
                bf16x8 b0 = *(const bf16x8*)(B + KOFF + R * 128 + ((hi * 16) ^ sw));
                bf16x8 b1 = *(const bf16x8*)(B + KOFF + R * 128 + ((64 + hi * 16) ^ sw));
                sacc[ni] = MFMA16(qf0, b0, sacc[ni]);
                sacc[ni] = MFMA16(qf1, b1, sacc[ni]);
            }
            // ---- R = Q ek_band^T -> own Rl ----
#pragma unroll
            for (int ni = 0; ni < 3; ++ni) {
                int n = nb + ni;
                int RL = (sub + n) * 16 + lo;
                f32x4 r = {};
                bf16x8 e0 = *(const bf16x8*)(B + EKOFF + RL * 128 + ((hi * 16) ^ sw));
                bf16x8 e1 = *(const bf16x8*)(B + EKOFF + RL * 128 + ((64 + hi * 16) ^ sw));
                r = MFMA16(qf0, e0, r);
                r = MFMA16(qf1, e1, r);
#pragma unroll
                for (int j = 0; j < 4; ++j) Rl[hi * 4 + j][n * 16 + lo] = f2bf(r[j]);
            }
            __builtin_amdgcn_s_setprio(0);
            // ---- combine + mask + exp2 (no staged reads; hides V/EV) ----
            float sv[2][4];
#pragma unroll
            for (int ni = 0; ni < 2; ++ni) {
                int sl = (2 * h + ni) * 16 + lo;
#pragma unroll
                for (int j = 0; j < 4; ++j) {
                    int r_ = hi * 4 + j;
                    sv[ni][j] = sacc[ni][j] + bf2f(Rl[r_][r_ - sl + 64]);
                }
            }
            asm volatile("" ::: "memory");
#pragma unroll
            for (int ni = 0; ni < 2; ++ni) {
                int sl = (2 * h + ni) * 16 + lo;
#pragma unroll
                for (int j = 0; j < 4; ++j) {
                    int r_ = hi * 4 + j;
                    float p = (!diag || sl <= sub * 16 + r_) ? exp2f(sv[ni][j]) : 0.0f;
                    rs[j] += p;
                    ushort pu = f2bf(p);
                    Pl[r_][sl] = pu;
                    Ppl[r_][r_ - sl + 64] = pu;
                }
            }
            asm volatile("" ::: "memory");

            // ---- phase B gate: V/EV of cur landed; next K/EK in flight ----
            if (ci + 1 < NC) asm volatile("s_waitcnt vmcnt(3)" ::: "memory");
            else             asm volatile("s_waitcnt vmcnt(0)" ::: "memory");
            __syncthreads();
            if (ci + 1 < NC) STAGE_VE(cur ^ 1, ci + 1);

            // ---- O += P V + P' embv_band ----
            __builtin_amdgcn_s_setprio(1);
            bf16x8 pa  = *(const bf16x8*)(&Pl[lo][h * 32 + hi * 8]);
            bf16x8 pb0 = *(const bf16x8*)(&Ppl[lo][kcA * 32 + hi * 8]);
            bf16x8 pb1 = *(const bf16x8*)(&Ppl[lo][kcB * 32 + hi * 8]);
#pragma unroll
            for (int n = 0; n < 4; ++n) {
                int R = n * 16 + lo;
                bf16x8 bv = *(const bf16x8*)(B + VOFF + R * 128 + ((h * 64 + hi * 16) ^ sw));
                O[n] = MFMA16(pa, bv, O[n]);
                bf16x8 e0 = *(const bf16x8*)(B + EVOFF + R * 384 +
                                             ((sub * 32 + kcA * 64 + hi * 16) ^ sw));
                O[n] = MFMA16(pb0, e0, O[n]);
                bf16x8 e1 = *(const bf16x8*)(B + EVOFF + R * 384 +
                                             ((sub * 32 + kcB * 64 + hi * 16) ^ sw));
                O[n] = MFMA16(pb1, e1, O[n]);
            }
            __builtin_amdgcn_s_setprio(0);
            asm volatile("" ::: "memory");   // P reads before next chunk's Rl writes
        }

        // ---- pair merge (fixed-point: partials just add) ----
#pragma unroll
        for (int msk = 1; msk < 16; msk <<= 1)
#pragma unroll
            for (int j = 0; j < 4; ++j) rs[j] += __shfl_xor(rs[j], msk);

        // merge scratch = the consumed buffer of the last chunk ((ci-1)&1);
        // in-flight DMA (chunk ci) targets the OTHER buffer.
        char* mscr = dls + ((ci - 1) & 1) * SBUF + sub * 8192;
        __syncthreads();   // all waves done with PV reads of consumed buffer
        if (h == 1) {
            float* Of = (float*)mscr;
#pragma unroll
            for (int n = 0; n < 4; ++n)
#pragma unroll
                for (int j = 0; j < 4; ++j)
                    Of[(hi * 4 + j) * 64 + n * 16 + lo] = O[n][j];
            if (lo == 0)
#pragma unroll
                for (int j = 0; j < 4; ++j)
                    ((float*)(mscr + 4096))[hi * 4 + j] = rs[j];
        }
        __syncthreads();
        if (h == 0) {
            float* Of = (float*)mscr;
            float inv[4];
#pragma unroll
            for (int j = 0; j < 4; ++j)
                inv[j] = 1.0f / (rs[j] + ((float*)(mscr + 4096))[hi * 4 + j]);
#pragma unroll
            for (int n = 0; n < 4; ++n)
#pragma unroll
                for (int j = 0; j < 4; ++j) {
                    int r = t0 + sub * 16 + hi * 4 + j;
                    float v = O[n][j] + Of[(hi * 4 + j) * 64 + n * 16 + lo];
                    y[((size_t)(b_ * 2048 + r)) * 256 + h_ * 64 + n * 16 + lo] =
                        f2bf(v * inv[j]);
                }
        }
        __syncthreads();   // merge reads done before tile B compute overwrites
    }
}

// ---------------------------------------------------------------------------
extern "C" void kernel_launch(void* const* d_in, const int* in_sizes, int n_in,
                              void* d_out, int out_size, void* d_ws, size_t ws_size,
                              hipStream_t stream) {
    const int*   tokens  = (const int*)d_in[0];
    const float* wte     = (const float*)d_in[1];
    const float* ln1_g   = (const float*)d_in[2];
    const float* ln1_b   = (const float*)d_in[3];
    const float* attn_w  = (const float*)d_in[4];
    const float* attn_b  = (const float*)d_in[5];
    const float* proj_w  = (const float*)d_in[6];
    const float* proj_b  = (const float*)d_in[7];
    const float* embk    = (const float*)d_in[8];
    const float* embv    = (const float*)d_in[9];
    const float* ln2_g   = (const float*)d_in[10];
    const float* ln2_b   = (const float*)d_in[11];
    const float* fc_w    = (const float*)d_in[12];
    const float* fc_b    = (const float*)d_in[13];
    const float* mproj_w = (const float*)d_in[14];
    const float* mproj_b = (const float*)d_in[15];
    const float* lnf_g   = (const float*)d_in[16];
    const float* lnf_b   = (const float*)d_in[17];
    const float* head_w  = (const float*)d_in[18];
    float* out = (float*)d_out;

    const int M = BB * TT;  // 8192
    char* wsb = (char*)d_ws;
    float*  x    = (float*)wsb;                               // 8 MB
    ushort* h    = (ushort*)(wsb + ((size_t)8 << 20));        // 4 MB
    ushort* y    = (ushort*)(wsb + ((size_t)12 << 20));       // 4 MB
    ushort* qb   = (ushort*)(wsb + ((size_t)16 << 20));       // 4 MB
    ushort* kbf  = (ushort*)(wsb + ((size_t)20 << 20));       // 4 MB
    ushort* vtb  = (ushort*)(wsb + ((size_t)24 << 20));       // 4 MB
    ushort* ekp  = (ushort*)(wsb + ((size_t)28 << 20));       // 2 x 278528 B
    ushort* evtp = ekp + (size_t)LL * EPAD * 64;              // 2 x 278528 B
    ushort* attn_wb  = (ushort*)(wsb + ((size_t)30 << 20));   // 3.7 MB total
    ushort* proj_wb  = attn_wb + (size_t)LL * 3 * CC * CC;
    ushort* fc_wb    = proj_wb + (size_t)LL * CC * CC;
    ushort* mproj_wb = fc_wb + (size_t)LL * 4 * CC * CC;
    ushort* head_wb  = mproj_wb + (size_t)LL * CC * 4 * CC;
    ushort* fcb = (ushort*)d_out;  // d_out reused as fc scratch (bf16)

    dim3 blk(256);
    const int FLDS = WSCR + 8 * 6144;        // 163840 B
    const int PLDS = 3 * 36864 + 1024;       // 111616 B
    hipFuncSetAttribute(reinterpret_cast<const void*>(flash_kernel),
                        hipFuncAttributeMaxDynamicSharedMemorySize, FLDS);
    hipFuncSetAttribute(reinterpret_cast<const void*>(bgemmln_kernel<4>),
                        hipFuncAttributeMaxDynamicSharedMemorySize, PLDS);
    hipFuncSetAttribute(reinterpret_cast<const void*>(bgemmln_kernel<16>),
                        hipFuncAttributeMaxDynamicSharedMemorySize, PLDS);

    prep_kernel<<<dim3(2880), blk, 0, stream>>>(
        attn_w, proj_w, fc_w, mproj_w, head_w,
        attn_wb, proj_wb, fc_wb, mproj_wb, head_wb,
        embk, embv, ekp, evtp);

    embed_ln_kernel<<<dim3(M / 4), blk, 0, stream>>>(
        tokens, wte, ln1_g, ln1_b, x, h);

    for (int l = 0; l < LL; l++) {
        bgemm256_kernel<3><<<dim3(6, 64), dim3(512), 0, stream>>>(
            h, attn_wb + (size_t)l * 3 * CC * CC, attn_b + (size_t)l * 3 * CC,
            nullptr, nullptr, 3 * CC, CC, qb, kbf, vtb);
        flash_kernel<<<dim3(256), dim3(512), FLDS, stream>>>(
            qb, kbf, vtb, ekp + (size_t)l * EPAD * 64, evtp + (size_t)l * 64 * EPAD, y);
        bgemmln_kernel<4><<<dim3(256), dim3(512), PLDS, stream>>>(
            y, proj_wb + (size_t)l * CC * CC, proj_b + (size_t)l * CC,
            x, ln2_g + l * CC, ln2_b + l * CC, h);
        bgemm256_kernel<2><<<dim3(8, 64), dim3(512), 0, stream>>>(
            h, fc_wb + (size_t)l * 4 * CC * CC, fc_b + (size_t)l * 4 * CC,
            nullptr, fcb, 4 * CC, CC, nullptr, nullptr, nullptr);
        const float* ng = (l == 0) ? (ln1_g + CC) : lnf_g;
        const float* nb = (l == 0) ? (ln1_b + CC) : lnf_b;
        bgemmln_kernel<16><<<dim3(256), dim3(512), PLDS, stream>>>(
            fcb, mproj_wb + (size_t)l * CC * 4 * CC, mproj_b + (size_t)l * CC,
            x, ng, nb, h);
    }

    bgemm256_kernel<0><<<dim3(8, 64), dim3(512), 0, stream>>>(
        h, head_wb, nullptr, out, nullptr, VV, CC, nullptr, nullptr, nullptr);
}

// Round 17
// 309.331 us; speedup vs baseline: 1.4193x; 1.0472x over previous
//
#include <hip/hip_runtime.h>
#include <hip/hip_bf16.h>
#include <math.h>

#define BB 4
#define TT 2048
#define CC 256
#define HH 4
#define LL 2
#define VV 1024
#define HS 64
#define EPAD 2176
#define LOG2E 1.4426950408889634f

typedef __attribute__((ext_vector_type(8))) __bf16 bf16x8;
typedef __attribute__((ext_vector_type(4))) float f32x4;

#define MFMA16(a, b, c) __builtin_amdgcn_mfma_f32_16x16x32_bf16((a), (b), (c), 0, 0, 0)

__device__ __forceinline__ ushort f2bf(float f) {
    __hip_bfloat16 h = __float2bfloat16(f);
    return *reinterpret_cast<ushort*>(&h);
}
__device__ __forceinline__ float bf2f(ushort u) {
    union { uint i; float f; } c; c.i = ((uint)u) << 16; return c.f;
}

__device__ __forceinline__ void gload16(const void* g, void* l) {
    __builtin_amdgcn_global_load_lds(
        (const __attribute__((address_space(1))) void*)g,
        (__attribute__((address_space(3))) void*)l, 16, 0, 0);
}

__device__ __forceinline__ float gelu_f(float v) {
    return 0.5f * v * (1.0f + tanhf(0.7978845608028654f * (v + 0.044715f * v * v * v)));
}

// ---------------------------------------------------------------------------
// prep: weight cvt (blocks 0..1791) + emb band cvt (1792..2879)
//       + embed+ln1[0] (2880..4927)  — all independent, one launch.
// ---------------------------------------------------------------------------
__global__ __launch_bounds__(256) void prep_kernel(
        const float* __restrict__ w0, const float* __restrict__ w1,
        const float* __restrict__ w2, const float* __restrict__ w3,
        const float* __restrict__ w4,
        ushort* __restrict__ o0, ushort* __restrict__ o1,
        ushort* __restrict__ o2, ushort* __restrict__ o3,
        ushort* __restrict__ o4,
        const float* __restrict__ ek, const float* __restrict__ ev,
        ushort* __restrict__ ekp, ushort* __restrict__ evtp,
        const int* __restrict__ tok, const float* __restrict__ wte,
        const float* __restrict__ lg, const float* __restrict__ lb,
        float* __restrict__ x, ushort* __restrict__ h) {
    int bi = blockIdx.x;
    if (bi < 1792) {
        int i = bi * 256 + threadIdx.x;
        const float* src; ushort* dst; int j;
        if (i < 98304)       { src = w0; dst = o0; j = i; }
        else if (i < 131072) { src = w1; dst = o1; j = i - 98304; }
        else if (i < 262144) { src = w2; dst = o2; j = i - 131072; }
        else if (i < 393216) { src = w3; dst = o3; j = i - 262144; }
        else                 { src = w4; dst = o4; j = i - 393216; }
        float4 v = ((const float4*)src)[j];
        ushort4 o;
        o.x = f2bf(v.x); o.y = f2bf(v.y); o.z = f2bf(v.z); o.w = f2bf(v.w);
        ((ushort4*)dst)[j] = o;
    } else if (bi < 2880) {
        int i = (bi - 1792) * 256 + threadIdx.x;   // over LL*EPAD*64
        int l = i / (EPAD * 64);
        int j = i - l * (EPAD * 64);
        int rp = j >> 6, d = j & 63;
        int o = rp - 64;
        bool in = (o >= 0 && o < TT);
        float kv = in ? ek[(size_t)l * TT * HS + (size_t)o * 64 + d] * LOG2E : 0.0f;
        float vv = in ? ev[(size_t)l * TT * HS + (size_t)o * 64 + d] : 0.0f;
        ekp[(size_t)l * EPAD * 64 + (size_t)rp * 64 + d] = f2bf(kv);
        evtp[(size_t)l * 64 * EPAD + (size_t)d * EPAD + rp] = f2bf(vv);
    } else {
        // embed + ln1[0]: one wave per row
        int row = (bi - 2880) * 4 + (threadIdx.x >> 6);
        int lane = threadIdx.x & 63;
        int tk = tok[row];
        float4 v = ((const float4*)(wte + (size_t)tk * CC))[lane];
        float s = v.x + v.y + v.z + v.w;
        float s2 = v.x * v.x + v.y * v.y + v.z * v.z + v.w * v.w;
        for (int m = 1; m < 64; m <<= 1) {
            s += __shfl_xor(s, m);
            s2 += __shfl_xor(s2, m);
        }
        float mean = s * (1.0f / CC);
        float var = s2 * (1.0f / CC) - mean * mean;
        float rs = rsqrtf(var + 1e-5f);
        float4 gg = ((const float4*)lg)[lane];
        float4 bb = ((const float4*)lb)[lane];
        ushort4 o;
        o.x = f2bf((v.x - mean) * rs * gg.x + bb.x);
        o.y = f2bf((v.y - mean) * rs * gg.y + bb.y);
        o.z = f2bf((v.z - mean) * rs * gg.z + bb.z);
        o.w = f2bf((v.w - mean) * rs * gg.w + bb.w);
        ((float4*)(x + (size_t)row * CC))[lane] = v;
        ((ushort4*)(h + (size_t)row * CC))[lane] = o;
    }
}

// ---------------------------------------------------------------------------
// bf16 MFMA GEMM, BM=128 x BN=128, BK=32, 8 waves (2x4).
// TRIPLE-buffered LDS + counted vmcnt.
// MODE: 0=store f32, 2=gelu->bf16, 3=qkv split->bf16 (vtb store vectorized)
// ---------------------------------------------------------------------------
template<int MODE>
__global__ __launch_bounds__(512) void bgemm256_kernel(
        const ushort* __restrict__ A, const ushort* __restrict__ W,
        const float* __restrict__ bias, float* __restrict__ out,
        ushort* __restrict__ outb, int N, int K,
        ushort* __restrict__ qb, ushort* __restrict__ kb,
        ushort* __restrict__ vtb) {
    constexpr int BUFSH = 16 * 512;           // 8192 ushorts = 16 KB per buf
    __shared__ ushort lds[3 * BUFSH];         // 48 KB
    int tid = threadIdx.x;
    int w = tid >> 6, lane = tid & 63;
    int lo = lane & 15, hi = lane >> 4;
    int row0 = blockIdx.y * 128;
    int col0 = blockIdx.x * 128;
    int wm = w >> 2, wn = w & 3;
    const ushort* Asrc = A + (size_t)row0 * K;
    const ushort* Wsrc = W + (size_t)col0 * K;

    auto STAGE = [&](int buf, int k0) {       // 2 loads per wave
        ushort* dst = &lds[buf * BUFSH];
        gload16(Asrc + (size_t)(w * 16 + lo) * K + k0 + hi * 8, dst + w * 512);
        gload16(Wsrc + (size_t)(w * 16 + lo) * K + k0 + hi * 8, dst + (8 + w) * 512);
    };

    f32x4 acc[4][2] = {};
    int NT = K >> 5;
    STAGE(0, 0);
    STAGE(1, 32);
    int cur = 0;
    for (int t = 0; t < NT; ++t) {
        if (t + 1 < NT) asm volatile("s_waitcnt vmcnt(2)" ::: "memory");
        else            asm volatile("s_waitcnt vmcnt(0)" ::: "memory");
        __syncthreads();
        if (t + 2 < NT) {
            int st = cur ? cur - 1 : 2;       // (t+2)%3
            STAGE(st, (t + 2) << 5);
        }
        bf16x8 a[4], b[2];
#pragma unroll
        for (int f = 0; f < 4; ++f)
            a[f] = *(const bf16x8*)&lds[cur * BUFSH + (wm * 4 + f) * 512 + lane * 8];
#pragma unroll
        for (int g = 0; g < 2; ++g)
            b[g] = *(const bf16x8*)&lds[cur * BUFSH + (8 + wn * 2 + g) * 512 + lane * 8];
        __builtin_amdgcn_s_setprio(1);
#pragma unroll
        for (int f = 0; f < 4; ++f)
#pragma unroll
            for (int g = 0; g < 2; ++g)
                acc[f][g] = MFMA16(a[f], b[g], acc[f][g]);
        __builtin_amdgcn_s_setprio(0);
        cur = cur < 2 ? cur + 1 : 0;
    }
#pragma unroll
    for (int f = 0; f < 4; ++f) {
        int rr = row0 + wm * 64 + f * 16 + hi * 4;
#pragma unroll
        for (int g = 0; g < 2; ++g) {
            int cc = col0 + wn * 32 + g * 16 + lo;
            float bv = bias ? bias[cc] : 0.0f;
            if (MODE == 3) {
                int bb2 = rr >> 11, t = rr & 2047;
                int which = cc >> 8, hh = (cc >> 6) & 3, dd = cc & 63;
                size_t bh = (size_t)(bb2 * 4 + hh);
                if (which == 2) {
                    // 4 consecutive t at one vtb row -> single ushort4 store
                    ushort4 o;
                    o.x = f2bf(acc[f][g][0] + bv);
                    o.y = f2bf(acc[f][g][1] + bv);
                    o.z = f2bf(acc[f][g][2] + bv);
                    o.w = f2bf(acc[f][g][3] + bv);
                    *(ushort4*)&vtb[(bh * 64 + dd) * 2048 + t] = o;
                } else if (which == 0) {
#pragma unroll
                    for (int j = 0; j < 4; ++j)
                        qb[(bh * 2048 + t + j) * 64 + dd] = f2bf(acc[f][g][j] + bv);
                } else {
#pragma unroll
                    for (int j = 0; j < 4; ++j)
                        kb[(bh * 2048 + t + j) * 64 + dd] =
                            f2bf((acc[f][g][j] + bv) * (0.125f * LOG2E));
                }
            } else {
#pragma unroll
                for (int j = 0; j < 4; ++j) {
                    int r = rr + j;
                    float v = acc[f][g][j] + bv;
                    if (MODE == 2) outb[(size_t)r * N + cc] = f2bf(gelu_f(v));
                    else           out[(size_t)r * N + cc] = v;
                }
            }
        }
    }
}

// ---------------------------------------------------------------------------
// Fused accumulate-GEMM + residual + LayerNorm. BM=32, BN=256 (full width),
// BK=64, 8 waves (2x4). TRIPLE-buffered counted-vmcnt pipeline.
// out: x (f32, residual updated) and h = LN(x) (bf16).  K = NSTEP*64.
// ---------------------------------------------------------------------------
template<int NSTEP>
__global__ __launch_bounds__(512) void bgemmln_kernel(
        const ushort* __restrict__ A, const ushort* __restrict__ W,
        const float* __restrict__ bias, float* __restrict__ x,
        const float* __restrict__ lng, const float* __restrict__ lnb,
        ushort* __restrict__ hout) {
    extern __shared__ ushort plds[];
    constexpr int K = NSTEP * 64;
    constexpr int BUFSH = 36 * 512;          // 18432 ushorts = 36 KB per buf
    int tid = threadIdx.x;
    int w = tid >> 6, lane = tid & 63;
    int lo = lane & 15, hi = lane >> 4;
    int row0 = blockIdx.x * 32;
    int wm = w >> 2, wn = w & 3;
    const ushort* Asrc = A + (size_t)row0 * K;

    auto STAGE = [&](int buf, int k0) {
        ushort* dst = &plds[buf * BUFSH];
        for (int s = w; s < 36; s += 8) {
            const ushort* src;
            if (s < 4) {
                int rg = s >> 1, kh = s & 1;
                src = Asrc + (size_t)(rg * 16 + lo) * K + k0 + kh * 32 + hi * 8;
            } else {
                int sb = s - 4, cg = sb >> 1, kh = sb & 1;
                src = W + (size_t)(cg * 16 + lo) * K + k0 + kh * 32 + hi * 8;
            }
            gload16(src, dst + s * 512);
        }
    };

    f32x4 acc[4] = {};
    STAGE(0, 0);
    STAGE(1, 64);
    int cur = 0;
    for (int t = 0; t < NSTEP; ++t) {
        if (t + 1 < NSTEP) {
            if (w < 4) asm volatile("s_waitcnt vmcnt(5)" ::: "memory");
            else       asm volatile("s_waitcnt vmcnt(4)" ::: "memory");
        } else {
            asm volatile("s_waitcnt vmcnt(0)" ::: "memory");
        }
        __syncthreads();
        if (t + 2 < NSTEP) {
            int st = cur ? cur - 1 : 2;       // (t+2)%3
            STAGE(st, (t + 2) << 6);
        }
        bf16x8 a[2];
#pragma unroll
        for (int kh = 0; kh < 2; ++kh)
            a[kh] = *(const bf16x8*)&plds[cur * BUFSH + (wm * 2 + kh) * 512 + lane * 8];
        __builtin_amdgcn_s_setprio(1);
#pragma unroll
        for (int g2 = 0; g2 < 4; ++g2) {
#pragma unroll
            for (int kh = 0; kh < 2; ++kh) {
                bf16x8 b = *(const bf16x8*)&plds[cur * BUFSH + 2048 +
                                                 ((wn * 4 + g2) * 2 + kh) * 512 + lane * 8];
                acc[g2] = MFMA16(a[kh], b, acc[g2]);
            }
        }
        __builtin_amdgcn_s_setprio(0);
        cur = cur < 2 ? cur + 1 : 0;
    }

    // ---- epilogue: v = acc + bias + x; row LN over 256 cols; write x, h ----
    float* part = (float*)&plds[3 * BUFSH];   // [2][32][4] floats (1 KB)
    float v[4][4];
    float s1[4] = {0, 0, 0, 0}, s2[4] = {0, 0, 0, 0};
#pragma unroll
    for (int g2 = 0; g2 < 4; ++g2) {
        int cc = wn * 64 + g2 * 16 + lo;
        float bv = bias[cc];
#pragma unroll
        for (int j = 0; j < 4; ++j) {
            int r = row0 + wm * 16 + hi * 4 + j;
            float tv = acc[g2][j] + bv + x[(size_t)r * CC + cc];
            v[g2][j] = tv;
            s1[j] += tv;
            s2[j] += tv * tv;
        }
    }
#pragma unroll
    for (int msk = 1; msk < 16; msk <<= 1)
#pragma unroll
        for (int j = 0; j < 4; ++j) {
            s1[j] += __shfl_xor(s1[j], msk);
            s2[j] += __shfl_xor(s2[j], msk);
        }
    if (lo == 0) {
#pragma unroll
        for (int j = 0; j < 4; ++j) {
            int rr = wm * 16 + hi * 4 + j;
            part[rr * 4 + wn] = s1[j];
            part[128 + rr * 4 + wn] = s2[j];
        }
    }
    __syncthreads();
#pragma unroll
    for (int j = 0; j < 4; ++j) {
        int rr = wm * 16 + hi * 4 + j;
        int r = row0 + rr;
        float4 p1 = *(float4*)&part[rr * 4];
        float4 p2 = *(float4*)&part[128 + rr * 4];
        float mean = (p1.x + p1.y + p1.z + p1.w) * (1.0f / CC);
        float var = (p2.x + p2.y + p2.z + p2.w) * (1.0f / CC) - mean * mean;
        float rsd = rsqrtf(var + 1e-5f);
#pragma unroll
        for (int g2 = 0; g2 < 4; ++g2) {
            int cc = wn * 64 + g2 * 16 + lo;
            x[(size_t)r * CC + cc] = v[g2][j];
            hout[(size_t)r * CC + cc] =
                f2bf((v[g2][j] - mean) * rsd * lng[cc] + lnb[cc]);
        }
    }
}

// ---------------------------------------------------------------------------
// Cooperative staged flash attention, 8 waves, fixed-point softmax.
// Per-chunk TWO-PHASE counted-vmcnt schedule (R14 — best measured, frozen).
// ---------------------------------------------------------------------------
#define SBUF 57344
#define KOFF 0
#define VOFF 8192
#define EKOFF 16384
#define EVOFF 32768
#define WSCR (2 * SBUF)

__global__ __launch_bounds__(512, 2) void flash_kernel(
        const ushort* __restrict__ qb,    // [16][2048][64]
        const ushort* __restrict__ kb,    // [16][2048][64] (pre-scaled 0.125*log2e)
        const ushort* __restrict__ vtb,   // [16][64][2048]
        const ushort* __restrict__ ekp,   // [EPAD][64]  (pre-scaled log2e)
        const ushort* __restrict__ evtp,  // [64][EPAD]
        ushort* __restrict__ y) {         // [B,T,C] bf16
    extern __shared__ __align__(16) char dls[];

    int g = blockIdx.x;
    int lbid = ((g & 7) << 5) | (g >> 3);
    int bh = lbid >> 4;
    int pk = lbid & 15;
    int tid = threadIdx.x;
    int w = tid >> 6;
    int sub = w & 3;
    int h = w >> 2;
    int lane = tid & 63;
    int lo = lane & 15, hi = lane >> 4;
    int sw = (lo & 7) << 4;

    char* wbase = dls + WSCR + w * 6144;
    ushort (*Rl)[88]   = (ushort (*)[88])  wbase;
    ushort (*Pl)[72]   = (ushort (*)[72])  wbase;
    ushort (*Ppl)[104] = (ushort (*)[104])(wbase + 2816);

    {
        uint* pz = reinterpret_cast<uint*>(&Ppl[0][0]);
        for (int i = lane; i < 832; i += 64) pz[i] = 0;
    }

    const char* kB  = (const char*)(kb  + (size_t)bh * 2048 * 64);
    const char* vB  = (const char*)(vtb + (size_t)bh * 64 * 2048);
    const char* ekB = (const char*)ekp;
    const char* evB = (const char*)evtp;

    int t0A = (31 - pk) * 64, t0B = pk * 64;
    int NSA = 32 - pk;
    const int NC = 33;

    auto STAGE_KE = [&](int buf, int ci) {    // 3 loads/thread: K + EK band
        int t0 = (ci < NSA) ? t0A : t0B;
        int s0 = ((ci < NSA) ? ci : ci - NSA) * 64;
        int band0 = t0 - s0;
        char* B = dls + buf * SBUF;
        int wb = (tid & 448) << 4;
        {
            int gb = tid * 16;
            int r = gb >> 7, c = gb & 127;
            gload16(kB + (size_t)(s0 + r) * 128 + (c ^ ((r & 7) << 4)), B + KOFF + wb);
        }
#pragma unroll
        for (int p = 0; p < 2; ++p) {
            int gb = p * 8192 + tid * 16;
            int r = gb >> 7, c = gb & 127;
            gload16(ekB + (size_t)(band0 + r) * 128 + (c ^ ((r & 7) << 4)),
                    B + EKOFF + p * 8192 + wb);
        }
    };
    auto STAGE_VE = [&](int buf, int ci) {    // 4 loads/thread: V + EV band
        int t0 = (ci < NSA) ? t0A : t0B;
        int s0 = ((ci < NSA) ? ci : ci - NSA) * 64;
        int band0 = t0 - s0;
        char* B = dls + buf * SBUF;
        int wb = (tid & 448) << 4;
        {
            int gb = tid * 16;
            int r = gb >> 7, c = gb & 127;
            gload16(vB + (size_t)r * 4096 + (size_t)s0 * 2 + (c ^ ((r & 7) << 4)),
                    B + VOFF + wb);
        }
#pragma unroll
        for (int p = 0; p < 3; ++p) {
            int gb = p * 8192 + tid * 16;
            int r = gb / 384, c = gb - r * 384;
            gload16(evB + (size_t)r * 4352 + (size_t)band0 * 2 + (c ^ ((r & 7) << 4)),
                    B + EVOFF + p * 8192 + wb);
        }
    };

    // prologue: Q fragments for both tiles FIRST (oldest in vmcnt order),
    // then chunk 0's stage.
    const ushort* qbaseA = qb + ((size_t)bh * 2048 + t0A + sub * 16) * 64;
    const ushort* qbaseB = qb + ((size_t)bh * 2048 + t0B + sub * 16) * 64;
    bf16x8 qfA0 = *(const bf16x8*)(qbaseA + (size_t)lo * 64 + hi * 8);
    bf16x8 qfA1 = *(const bf16x8*)(qbaseA + (size_t)lo * 64 + 32 + hi * 8);
    bf16x8 qfB0 = *(const bf16x8*)(qbaseB + (size_t)lo * 64 + hi * 8);
    bf16x8 qfB1 = *(const bf16x8*)(qbaseB + (size_t)lo * 64 + 32 + hi * 8);
    STAGE_KE(0, 0);
    STAGE_VE(0, 0);

    int b_ = bh >> 2, h_ = bh & 3;
    int ci = 0;
    int nb = h ? 0 : 2;
    int kcA = h ? 0 : 1, kcB = h ? 1 : 2;

    for (int tile = 0; tile < 2; ++tile) {
        int t0 = tile ? t0B : t0A;
        int NS = tile ? (pk + 1) : NSA;
        bf16x8 qf0 = tile ? qfB0 : qfA0;
        bf16x8 qf1 = tile ? qfB1 : qfA1;

        float rs[4] = {0.0f, 0.0f, 0.0f, 0.0f};
        f32x4 O[4] = {};

        for (int c = 0; c < NS; ++c, ++ci) {
            int cur = ci & 1;
            const char* B = dls + cur * SBUF;
            bool diag = (c == NS - 1);

            // ---- phase A gate: K/EK of cur landed; V/EV still in flight ----
            asm volatile("s_waitcnt vmcnt(4)" ::: "memory");
            __syncthreads();
            if (ci + 1 < NC) STAGE_KE(cur ^ 1, ci + 1);

            // ---- S = Q K^T ----
            f32x4 sacc[2] = {};
            __builtin_amdgcn_s_setprio(1);
#pragma unroll
            for (int ni = 0; ni < 2; ++ni) {
                int R = (2 * h + ni) * 16 + lo;
                bf16x8 b0 = *(const bf16x8*)(B + KOFF + R * 128 + ((hi * 16) ^ sw));
                bf16x8 b1 = *(const bf16x8*)(B + KOFF + R * 128 + ((64 + hi * 16) ^ sw));
                sacc[ni] = MFMA16(qf0, b0, sacc[ni]);
                sacc[ni] = MFMA16(qf1, b1, sacc[ni]);
            }
            // ---- R = Q ek_band^T -> own Rl ----
#pragma unroll
            for (int ni = 0; ni < 3; ++ni) {
                int n = nb + ni;
                int RL = (sub + n) * 16 + lo;
                f32x4 r = {};
                bf16x8 e0 = *(const bf16x8*)(B + EKOFF + RL * 128 + ((hi * 16) ^ sw));
                bf16x8 e1 = *(const bf16x8*)(B + EKOFF + RL * 128 + ((64 + hi * 16) ^ sw));
                r = MFMA16(qf0, e0, r);
                r = MFMA16(qf1, e1, r);
#pragma unroll
                for (int j = 0; j < 4; ++j) Rl[hi * 4 + j][n * 16 + lo] = f2bf(r[j]);
            }
            __builtin_amdgcn_s_setprio(0);
            // ---- combine + mask + exp2 (no staged reads; hides V/EV) ----
            float sv[2][4];
#pragma unroll
            for (int ni = 0; ni < 2; ++ni) {
                int sl = (2 * h + ni) * 16 + lo;
#pragma unroll
                for (int j = 0; j < 4; ++j) {
                    int r_ = hi * 4 + j;
                    sv[ni][j] = sacc[ni][j] + bf2f(Rl[r_][r_ - sl + 64]);
                }
            }
            asm volatile("" ::: "memory");
#pragma unroll
            for (int ni = 0; ni < 2; ++ni) {
                int sl = (2 * h + ni) * 16 + lo;
#pragma unroll
                for (int j = 0; j < 4; ++j) {
                    int r_ = hi * 4 + j;
                    float p = (!diag || sl <= sub * 16 + r_) ? exp2f(sv[ni][j]) : 0.0f;
                    rs[j] += p;
                    ushort pu = f2bf(p);
                    Pl[r_][sl] = pu;
                    Ppl[r_][r_ - sl + 64] = pu;
                }
            }
            asm volatile("" ::: "memory");

            // ---- phase B gate: V/EV of cur landed; next K/EK in flight ----
            if (ci + 1 < NC) asm volatile("s_waitcnt vmcnt(3)" ::: "memory");
            else             asm volatile("s_waitcnt vmcnt(0)" ::: "memory");
            __syncthreads();
            if (ci + 1 < NC) STAGE_VE(cur ^ 1, ci + 1);

            // ---- O += P V + P' embv_band ----
            __builtin_amdgcn_s_setprio(1);
            bf16x8 pa  = *(const bf16x8*)(&Pl[lo][h * 32 + hi * 8]);
            bf16x8 pb0 = *(const bf16x8*)(&Ppl[lo][kcA * 32 + hi * 8]);
            bf16x8 pb1 = *(const bf16x8*)(&Ppl[lo][kcB * 32 + hi * 8]);
#pragma unroll
            for (int n = 0; n < 4; ++n) {
                int R = n * 16 + lo;
                bf16x8 bv = *(const bf16x8*)(B + VOFF + R * 128 + ((h * 64 + hi * 16) ^ sw));
                O[n] = MFMA16(pa, bv, O[n]);
                bf16x8 e0 = *(const bf16x8*)(B + EVOFF + R * 384 +
                                             ((sub * 32 + kcA * 64 + hi * 16) ^ sw));
                O[n] = MFMA16(pb0, e0, O[n]);
                bf16x8 e1 = *(const bf16x8*)(B + EVOFF + R * 384 +
                                             ((sub * 32 + kcB * 64 + hi * 16) ^ sw));
                O[n] = MFMA16(pb1, e1, O[n]);
            }
            __builtin_amdgcn_s_setprio(0);
            asm volatile("" ::: "memory");   // P reads before next chunk's Rl writes
        }

        // ---- pair merge (fixed-point: partials just add) ----
#pragma unroll
        for (int msk = 1; msk < 16; msk <<= 1)
#pragma unroll
            for (int j = 0; j < 4; ++j) rs[j] += __shfl_xor(rs[j], msk);

        // merge scratch = the consumed buffer of the last chunk ((ci-1)&1);
        // in-flight DMA (chunk ci) targets the OTHER buffer.
        char* mscr = dls + ((ci - 1) & 1) * SBUF + sub * 8192;
        __syncthreads();   // all waves done with PV reads of consumed buffer
        if (h == 1) {
            float* Of = (float*)mscr;
#pragma unroll
            for (int n = 0; n < 4; ++n)
#pragma unroll
                for (int j = 0; j < 4; ++j)
                    Of[(hi * 4 + j) * 64 + n * 16 + lo] = O[n][j];
            if (lo == 0)
#pragma unroll
                for (int j = 0; j < 4; ++j)
                    ((float*)(mscr + 4096))[hi * 4 + j] = rs[j];
        }
        __syncthreads();
        if (h == 0) {
            float* Of = (float*)mscr;
            float inv[4];
#pragma unroll
            for (int j = 0; j < 4; ++j)
                inv[j] = 1.0f / (rs[j] + ((float*)(mscr + 4096))[hi * 4 + j]);
#pragma unroll
            for (int n = 0; n < 4; ++n)
#pragma unroll
                for (int j = 0; j < 4; ++j) {
                    int r = t0 + sub * 16 + hi * 4 + j;
                    float v = O[n][j] + Of[(hi * 4 + j) * 64 + n * 16 + lo];
                    y[((size_t)(b_ * 2048 + r)) * 256 + h_ * 64 + n * 16 + lo] =
                        f2bf(v * inv[j]);
                }
        }
        __syncthreads();   // merge reads done before tile B compute overwrites
    }
}

// ---------------------------------------------------------------------------
extern "C" void kernel_launch(void* const* d_in, const int* in_sizes, int n_in,
                              void* d_out, int out_size, void* d_ws, size_t ws_size,
                              hipStream_t stream) {
    const int*   tokens  = (const int*)d_in[0];
    const float* wte     = (const float*)d_in[1];
    const float* ln1_g   = (const float*)d_in[2];
    const float* ln1_b   = (const float*)d_in[3];
    const float* attn_w  = (const float*)d_in[4];
    const float* attn_b  = (const float*)d_in[5];
    const float* proj_w  = (const float*)d_in[6];
    const float* proj_b  = (const float*)d_in[7];
    const float* embk    = (const float*)d_in[8];
    const float* embv    = (const float*)d_in[9];
    const float* ln2_g   = (const float*)d_in[10];
    const float* ln2_b   = (const float*)d_in[11];
    const float* fc_w    = (const float*)d_in[12];
    const float* fc_b    = (const float*)d_in[13];
    const float* mproj_w = (const float*)d_in[14];
    const float* mproj_b = (const float*)d_in[15];
    const float* lnf_g   = (const float*)d_in[16];
    const float* lnf_b   = (const float*)d_in[17];
    const float* head_w  = (const float*)d_in[18];
    float* out = (float*)d_out;

    const int M = BB * TT;  // 8192
    char* wsb = (char*)d_ws;
    float*  x    = (float*)wsb;                               // 8 MB
    ushort* h    = (ushort*)(wsb + ((size_t)8 << 20));        // 4 MB
    ushort* y    = (ushort*)(wsb + ((size_t)12 << 20));       // 4 MB
    ushort* qb   = (ushort*)(wsb + ((size_t)16 << 20));       // 4 MB
    ushort* kbf  = (ushort*)(wsb + ((size_t)20 << 20));       // 4 MB
    ushort* vtb  = (ushort*)(wsb + ((size_t)24 << 20));       // 4 MB
    ushort* ekp  = (ushort*)(wsb + ((size_t)28 << 20));       // 2 x 278528 B
    ushort* evtp = ekp + (size_t)LL * EPAD * 64;              // 2 x 278528 B
    ushort* attn_wb  = (ushort*)(wsb + ((size_t)30 << 20));   // 3.7 MB total
    ushort* proj_wb  = attn_wb + (size_t)LL * 3 * CC * CC;
    ushort* fc_wb    = proj_wb + (size_t)LL * CC * CC;
    ushort* mproj_wb = fc_wb + (size_t)LL * 4 * CC * CC;
    ushort* head_wb  = mproj_wb + (size_t)LL * CC * 4 * CC;
    ushort* fcb = (ushort*)d_out;  // d_out reused as fc scratch (bf16)

    dim3 blk(256);
    const int FLDS = WSCR + 8 * 6144;        // 163840 B
    const int PLDS = 3 * 36864 + 1024;       // 111616 B
    hipFuncSetAttribute(reinterpret_cast<const void*>(flash_kernel),
                        hipFuncAttributeMaxDynamicSharedMemorySize, FLDS);
    hipFuncSetAttribute(reinterpret_cast<const void*>(bgemmln_kernel<4>),
                        hipFuncAttributeMaxDynamicSharedMemorySize, PLDS);
    hipFuncSetAttribute(reinterpret_cast<const void*>(bgemmln_kernel<16>),
                        hipFuncAttributeMaxDynamicSharedMemorySize, PLDS);

    // prep (weights + emb bands) and embed+ln1[0] in ONE launch
    prep_kernel<<<dim3(2880 + M / 4), blk, 0, stream>>>(
        attn_w, proj_w, fc_w, mproj_w, head_w,
        attn_wb, proj_wb, fc_wb, mproj_wb, head_wb,
        embk, embv, ekp, evtp,
        tokens, wte, ln1_g, ln1_b, x, h);

    for (int l = 0; l < LL; l++) {
        bgemm256_kernel<3><<<dim3(6, 64), dim3(512), 0, stream>>>(
            h, attn_wb + (size_t)l * 3 * CC * CC, attn_b + (size_t)l * 3 * CC,
            nullptr, nullptr, 3 * CC, CC, qb, kbf, vtb);
        flash_kernel<<<dim3(256), dim3(512), FLDS, stream>>>(
            qb, kbf, vtb, ekp + (size_t)l * EPAD * 64, evtp + (size_t)l * 64 * EPAD, y);
        bgemmln_kernel<4><<<dim3(256), dim3(512), PLDS, stream>>>(
            y, proj_wb + (size_t)l * CC * CC, proj_b + (size_t)l * CC,
            x, ln2_g + l * CC, ln2_b + l * CC, h);
        bgemm256_kernel<2><<<dim3(8, 64), dim3(512), 0, stream>>>(
            h, fc_wb + (size_t)l * 4 * CC * CC, fc_b + (size_t)l * 4 * CC,
            nullptr, fcb, 4 * CC, CC, nullptr, nullptr, nullptr);
        const float* ng = (l == 0) ? (ln1_g + CC) : lnf_g;
        const float* nb = (l == 0) ? (ln1_b + CC) : lnf_b;
        bgemmln_kernel<16><<<dim3(256), dim3(512), PLDS, stream>>>(
            fcb, mproj_wb + (size_t)l * CC * 4 * CC, mproj_b + (size_t)l * CC,
            x, ng, nb, h);
    }

    bgemm256_kernel<0><<<dim3(8, 64), dim3(512), 0, stream>>>(
        h, head_wb, nullptr, out, nullptr, VV, CC, nullptr, nullptr, nullptr);
}

// Round 18
// 309.165 us; speedup vs baseline: 1.4200x; 1.0005x over previous
//
#include <hip/hip_runtime.h>
#include <hip/hip_bf16.h>
#include <math.h>

#define BB 4
#define TT 2048
#define CC 256
#define HH 4
#define LL 2
#define VV 1024
#define HS 64
#define EPAD 2176
#define LOG2E 1.4426950408889634f

typedef __attribute__((ext_vector_type(8))) __bf16 bf16x8;
typedef __attribute__((ext_vector_type(4))) float f32x4;

#define MFMA16(a, b, c) __builtin_amdgcn_mfma_f32_16x16x32_bf16((a), (b), (c), 0, 0, 0)

__device__ __forceinline__ ushort f2bf(float f) {
    __hip_bfloat16 h = __float2bfloat16(f);
    return *reinterpret_cast<ushort*>(&h);
}
__device__ __forceinline__ float bf2f(ushort u) {
    union { uint i; float f; } c; c.i = ((uint)u) << 16; return c.f;
}

__device__ __forceinline__ void gload16(const void* g, void* l) {
    __builtin_amdgcn_global_load_lds(
        (const __attribute__((address_space(1))) void*)g,
        (__attribute__((address_space(3))) void*)l, 16, 0, 0);
}

__device__ __forceinline__ float gelu_f(float v) {
    return 0.5f * v * (1.0f + tanhf(0.7978845608028654f * (v + 0.044715f * v * v * v)));
}

// ---------------------------------------------------------------------------
// prep: weight cvt (blocks 0..1791) + emb band cvt (1792..2879)
//       + embed+ln1[0] (2880..4927)  — all independent, one launch.
// ---------------------------------------------------------------------------
__global__ __launch_bounds__(256) void prep_kernel(
        const float* __restrict__ w0, const float* __restrict__ w1,
        const float* __restrict__ w2, const float* __restrict__ w3,
        const float* __restrict__ w4,
        ushort* __restrict__ o0, ushort* __restrict__ o1,
        ushort* __restrict__ o2, ushort* __restrict__ o3,
        ushort* __restrict__ o4,
        const float* __restrict__ ek, const float* __restrict__ ev,
        ushort* __restrict__ ekp, ushort* __restrict__ evtp,
        const int* __restrict__ tok, const float* __restrict__ wte,
        const float* __restrict__ lg, const float* __restrict__ lb,
        float* __restrict__ x, ushort* __restrict__ h) {
    int bi = blockIdx.x;
    if (bi < 1792) {
        int i = bi * 256 + threadIdx.x;
        const float* src; ushort* dst; int j;
        if (i < 98304)       { src = w0; dst = o0; j = i; }
        else if (i < 131072) { src = w1; dst = o1; j = i - 98304; }
        else if (i < 262144) { src = w2; dst = o2; j = i - 131072; }
        else if (i < 393216) { src = w3; dst = o3; j = i - 262144; }
        else                 { src = w4; dst = o4; j = i - 393216; }
        float4 v = ((const float4*)src)[j];
        ushort4 o;
        o.x = f2bf(v.x); o.y = f2bf(v.y); o.z = f2bf(v.z); o.w = f2bf(v.w);
        ((ushort4*)dst)[j] = o;
    } else if (bi < 2880) {
        int i = (bi - 1792) * 256 + threadIdx.x;   // over LL*EPAD*64
        int l = i / (EPAD * 64);
        int j = i - l * (EPAD * 64);
        int rp = j >> 6, d = j & 63;
        int o = rp - 64;
        bool in = (o >= 0 && o < TT);
        float kv = in ? ek[(size_t)l * TT * HS + (size_t)o * 64 + d] * LOG2E : 0.0f;
        float vv = in ? ev[(size_t)l * TT * HS + (size_t)o * 64 + d] : 0.0f;
        ekp[(size_t)l * EPAD * 64 + (size_t)rp * 64 + d] = f2bf(kv);
        evtp[(size_t)l * 64 * EPAD + (size_t)d * EPAD + rp] = f2bf(vv);
    } else {
        // embed + ln1[0]: one wave per row
        int row = (bi - 2880) * 4 + (threadIdx.x >> 6);
        int lane = threadIdx.x & 63;
        int tk = tok[row];
        float4 v = ((const float4*)(wte + (size_t)tk * CC))[lane];
        float s = v.x + v.y + v.z + v.w;
        float s2 = v.x * v.x + v.y * v.y + v.z * v.z + v.w * v.w;
        for (int m = 1; m < 64; m <<= 1) {
            s += __shfl_xor(s, m);
            s2 += __shfl_xor(s2, m);
        }
        float mean = s * (1.0f / CC);
        float var = s2 * (1.0f / CC) - mean * mean;
        float rs = rsqrtf(var + 1e-5f);
        float4 gg = ((const float4*)lg)[lane];
        float4 bb = ((const float4*)lb)[lane];
        ushort4 o;
        o.x = f2bf((v.x - mean) * rs * gg.x + bb.x);
        o.y = f2bf((v.y - mean) * rs * gg.y + bb.y);
        o.z = f2bf((v.z - mean) * rs * gg.z + bb.z);
        o.w = f2bf((v.w - mean) * rs * gg.w + bb.w);
        ((float4*)(x + (size_t)row * CC))[lane] = v;
        ((ushort4*)(h + (size_t)row * CC))[lane] = o;
    }
}

// ---------------------------------------------------------------------------
// QKV GEMM, BM=128 x BN=64, BK=32, 8 waves (2 wm x 4 wn), grid (12,64)=768
// blocks = exactly 3 blocks/CU (balanced; the old (6,64)=1.5/CU wasn't).
// Triple-buffered counted-vmcnt; waves 0-3 stage 2 subtiles/step (A+B),
// waves 4-7 stage 1 (A) -> per-wave wait counts 2/1.
// Epilogue: qkv split->bf16 (vtb store vectorized).
// ---------------------------------------------------------------------------
__global__ __launch_bounds__(512) void bgemmqkv_kernel(
        const ushort* __restrict__ A, const ushort* __restrict__ W,
        const float* __restrict__ bias,
        ushort* __restrict__ qb, ushort* __restrict__ kb,
        ushort* __restrict__ vtb) {
    constexpr int K = 256;
    constexpr int BUFSH = 12 * 512;           // 6144 ushorts = 12 KB per buf
    __shared__ ushort lds[3 * BUFSH];         // 36 KB
    int tid = threadIdx.x;
    int w = tid >> 6, lane = tid & 63;
    int lo = lane & 15, hi = lane >> 4;
    int row0 = blockIdx.y * 128;
    int col0 = blockIdx.x * 64;
    int wm = w >> 2, wn = w & 3;
    const ushort* Asrc = A + (size_t)row0 * K;
    const ushort* Wsrc = W + (size_t)col0 * K;

    auto STAGE = [&](int buf, int k0) {       // A subtile w; waves 0-3 also B subtile w
        ushort* dst = &lds[buf * BUFSH];
        gload16(Asrc + (size_t)(w * 16 + lo) * K + k0 + hi * 8, dst + w * 512);
        if (w < 4)
            gload16(Wsrc + (size_t)(w * 16 + lo) * K + k0 + hi * 8, dst + (8 + w) * 512);
    };

    f32x4 acc[4] = {};
    constexpr int NT = K >> 5;                // 8 steps
    STAGE(0, 0);
    STAGE(1, 32);
    int cur = 0;
    for (int t = 0; t < NT; ++t) {
        if (t + 1 < NT) {
            if (w < 4) asm volatile("s_waitcnt vmcnt(2)" ::: "memory");
            else       asm volatile("s_waitcnt vmcnt(1)" ::: "memory");
        } else {
            asm volatile("s_waitcnt vmcnt(0)" ::: "memory");
        }
        __syncthreads();
        if (t + 2 < NT) {
            int st = cur ? cur - 1 : 2;       // (t+2)%3
            STAGE(st, (t + 2) << 5);
        }
        bf16x8 a[4], b;
#pragma unroll
        for (int f = 0; f < 4; ++f)
            a[f] = *(const bf16x8*)&lds[cur * BUFSH + (wm * 4 + f) * 512 + lane * 8];
        b = *(const bf16x8*)&lds[cur * BUFSH + (8 + wn) * 512 + lane * 8];
        __builtin_amdgcn_s_setprio(1);
#pragma unroll
        for (int f = 0; f < 4; ++f)
            acc[f] = MFMA16(a[f], b, acc[f]);
        __builtin_amdgcn_s_setprio(0);
        cur = cur < 2 ? cur + 1 : 0;
    }
#pragma unroll
    for (int f = 0; f < 4; ++f) {
        int rr = row0 + wm * 64 + f * 16 + hi * 4;
        int cc = col0 + wn * 16 + lo;
        float bv = bias[cc];
        int bb2 = rr >> 11, t = rr & 2047;
        int which = cc >> 8, hh = (cc >> 6) & 3, dd = cc & 63;
        size_t bh = (size_t)(bb2 * 4 + hh);
        if (which == 2) {
            ushort4 o;
            o.x = f2bf(acc[f][0] + bv);
            o.y = f2bf(acc[f][1] + bv);
            o.z = f2bf(acc[f][2] + bv);
            o.w = f2bf(acc[f][3] + bv);
            *(ushort4*)&vtb[(bh * 64 + dd) * 2048 + t] = o;
        } else if (which == 0) {
#pragma unroll
            for (int j = 0; j < 4; ++j)
                qb[(bh * 2048 + t + j) * 64 + dd] = f2bf(acc[f][j] + bv);
        } else {
#pragma unroll
            for (int j = 0; j < 4; ++j)
                kb[(bh * 2048 + t + j) * 64 + dd] =
                    f2bf((acc[f][j] + bv) * (0.125f * LOG2E));
        }
    }
}

// ---------------------------------------------------------------------------
// bf16 MFMA GEMM, BM=128 x BN=128, BK=32, 8 waves (2x4).
// TRIPLE-buffered LDS + counted vmcnt.
// MODE: 0=store f32, 2=gelu->bf16
// ---------------------------------------------------------------------------
template<int MODE>
__global__ __launch_bounds__(512) void bgemm256_kernel(
        const ushort* __restrict__ A, const ushort* __restrict__ W,
        const float* __restrict__ bias, float* __restrict__ out,
        ushort* __restrict__ outb, int N, int K) {
    constexpr int BUFSH = 16 * 512;           // 8192 ushorts = 16 KB per buf
    __shared__ ushort lds[3 * BUFSH];         // 48 KB
    int tid = threadIdx.x;
    int w = tid >> 6, lane = tid & 63;
    int lo = lane & 15, hi = lane >> 4;
    int row0 = blockIdx.y * 128;
    int col0 = blockIdx.x * 128;
    int wm = w >> 2, wn = w & 3;
    const ushort* Asrc = A + (size_t)row0 * K;
    const ushort* Wsrc = W + (size_t)col0 * K;

    auto STAGE = [&](int buf, int k0) {       // 2 loads per wave
        ushort* dst = &lds[buf * BUFSH];
        gload16(Asrc + (size_t)(w * 16 + lo) * K + k0 + hi * 8, dst + w * 512);
        gload16(Wsrc + (size_t)(w * 16 + lo) * K + k0 + hi * 8, dst + (8 + w) * 512);
    };

    f32x4 acc[4][2] = {};
    int NT = K >> 5;
    STAGE(0, 0);
    STAGE(1, 32);
    int cur = 0;
    for (int t = 0; t < NT; ++t) {
        if (t + 1 < NT) asm volatile("s_waitcnt vmcnt(2)" ::: "memory");
        else            asm volatile("s_waitcnt vmcnt(0)" ::: "memory");
        __syncthreads();
        if (t + 2 < NT) {
            int st = cur ? cur - 1 : 2;       // (t+2)%3
            STAGE(st, (t + 2) << 5);
        }
        bf16x8 a[4], b[2];
#pragma unroll
        for (int f = 0; f < 4; ++f)
            a[f] = *(const bf16x8*)&lds[cur * BUFSH + (wm * 4 + f) * 512 + lane * 8];
#pragma unroll
        for (int g = 0; g < 2; ++g)
            b[g] = *(const bf16x8*)&lds[cur * BUFSH + (8 + wn * 2 + g) * 512 + lane * 8];
        __builtin_amdgcn_s_setprio(1);
#pragma unroll
        for (int f = 0; f < 4; ++f)
#pragma unroll
            for (int g = 0; g < 2; ++g)
                acc[f][g] = MFMA16(a[f], b[g], acc[f][g]);
        __builtin_amdgcn_s_setprio(0);
        cur = cur < 2 ? cur + 1 : 0;
    }
#pragma unroll
    for (int f = 0; f < 4; ++f) {
        int rr = row0 + wm * 64 + f * 16 + hi * 4;
#pragma unroll
        for (int g = 0; g < 2; ++g) {
            int cc = col0 + wn * 32 + g * 16 + lo;
            float bv = bias ? bias[cc] : 0.0f;
#pragma unroll
            for (int j = 0; j < 4; ++j) {
                int r = rr + j;
                float v = acc[f][g][j] + bv;
                if (MODE == 2) outb[(size_t)r * N + cc] = f2bf(gelu_f(v));
                else           out[(size_t)r * N + cc] = v;
            }
        }
    }
}

// ---------------------------------------------------------------------------
// Fused accumulate-GEMM + residual + LayerNorm. BM=32, BN=256 (full width),
// BK=64, 8 waves (2x4). TRIPLE-buffered counted-vmcnt pipeline.
// out: x (f32, residual updated) and h = LN(x) (bf16).  K = NSTEP*64.
// ---------------------------------------------------------------------------
template<int NSTEP>
__global__ __launch_bounds__(512) void bgemmln_kernel(
        const ushort* __restrict__ A, const ushort* __restrict__ W,
        const float* __restrict__ bias, float* __restrict__ x,
        const float* __restrict__ lng, const float* __restrict__ lnb,
        ushort* __restrict__ hout) {
    extern __shared__ ushort plds[];
    constexpr int K = NSTEP * 64;
    constexpr int BUFSH = 36 * 512;          // 18432 ushorts = 36 KB per buf
    int tid = threadIdx.x;
    int w = tid >> 6, lane = tid & 63;
    int lo = lane & 15, hi = lane >> 4;
    int row0 = blockIdx.x * 32;
    int wm = w >> 2, wn = w & 3;
    const ushort* Asrc = A + (size_t)row0 * K;

    auto STAGE = [&](int buf, int k0) {
        ushort* dst = &plds[buf * BUFSH];
        for (int s = w; s < 36; s += 8) {
            const ushort* src;
            if (s < 4) {
                int rg = s >> 1, kh = s & 1;
                src = Asrc + (size_t)(rg * 16 + lo) * K + k0 + kh * 32 + hi * 8;
            } else {
                int sb = s - 4, cg = sb >> 1, kh = sb & 1;
                src = W + (size_t)(cg * 16 + lo) * K + k0 + kh * 32 + hi * 8;
            }
            gload16(src, dst + s * 512);
        }
    };

    f32x4 acc[4] = {};
    STAGE(0, 0);
    STAGE(1, 64);
    int cur = 0;
    for (int t = 0; t < NSTEP; ++t) {
        if (t + 1 < NSTEP) {
            if (w < 4) asm volatile("s_waitcnt vmcnt(5)" ::: "memory");
            else       asm volatile("s_waitcnt vmcnt(4)" ::: "memory");
        } else {
            asm volatile("s_waitcnt vmcnt(0)" ::: "memory");
        }
        __syncthreads();
        if (t + 2 < NSTEP) {
            int st = cur ? cur - 1 : 2;       // (t+2)%3
            STAGE(st, (t + 2) << 6);
        }
        bf16x8 a[2];
#pragma unroll
        for (int kh = 0; kh < 2; ++kh)
            a[kh] = *(const bf16x8*)&plds[cur * BUFSH + (wm * 2 + kh) * 512 + lane * 8];
        __builtin_amdgcn_s_setprio(1);
#pragma unroll
        for (int g2 = 0; g2 < 4; ++g2) {
#pragma unroll
            for (int kh = 0; kh < 2; ++kh) {
                bf16x8 b = *(const bf16x8*)&plds[cur * BUFSH + 2048 +
                                                 ((wn * 4 + g2) * 2 + kh) * 512 + lane * 8];
                acc[g2] = MFMA16(a[kh], b, acc[g2]);
            }
        }
        __builtin_amdgcn_s_setprio(0);
        cur = cur < 2 ? cur + 1 : 0;
    }

    // ---- epilogue: v = acc + bias + x; row LN over 256 cols; write x, h ----
    float* part = (float*)&plds[3 * BUFSH];   // [2][32][4] floats (1 KB)
    float v[4][4];
    float s1[4] = {0, 0, 0, 0}, s2[4] = {0, 0, 0, 0};
#pragma unroll
    for (int g2 = 0; g2 < 4; ++g2) {
        int cc = wn * 64 + g2 * 16 + lo;
        float bv = bias[cc];
#pragma unroll
        for (int j = 0; j < 4; ++j) {
            int r = row0 + wm * 16 + hi * 4 + j;
            float tv = acc[g2][j] + bv + x[(size_t)r * CC + cc];
            v[g2][j] = tv;
            s1[j] += tv;
            s2[j] += tv * tv;
        }
    }
#pragma unroll
    for (int msk = 1; msk < 16; msk <<= 1)
#pragma unroll
        for (int j = 0; j < 4; ++j) {
            s1[j] += __shfl_xor(s1[j], msk);
            s2[j] += __shfl_xor(s2[j], msk);
        }
    if (lo == 0) {
#pragma unroll
        for (int j = 0; j < 4; ++j) {
            int rr = wm * 16 + hi * 4 + j;
            part[rr * 4 + wn] = s1[j];
            part[128 + rr * 4 + wn] = s2[j];
        }
    }
    __syncthreads();
#pragma unroll
    for (int j = 0; j < 4; ++j) {
        int rr = wm * 16 + hi * 4 + j;
        int r = row0 + rr;
        float4 p1 = *(float4*)&part[rr * 4];
        float4 p2 = *(float4*)&part[128 + rr * 4];
        float mean = (p1.x + p1.y + p1.z + p1.w) * (1.0f / CC);
        float var = (p2.x + p2.y + p2.z + p2.w) * (1.0f / CC) - mean * mean;
        float rsd = rsqrtf(var + 1e-5f);
#pragma unroll
        for (int g2 = 0; g2 < 4; ++g2) {
            int cc = wn * 64 + g2 * 16 + lo;
            x[(size_t)r * CC + cc] = v[g2][j];
            hout[(size_t)r * CC + cc] =
                f2bf((v[g2][j] - mean) * rsd * lng[cc] + lnb[cc]);
        }
    }
}

// ---------------------------------------------------------------------------
// Cooperative staged flash attention, 8 waves, fixed-point softmax.
// Per-chunk TWO-PHASE counted-vmcnt schedule (R14 — best measured, frozen).
// ---------------------------------------------------------------------------
#define SBUF 57344
#define KOFF 0
#define VOFF 8192
#define EKOFF 16384
#define EVOFF 32768
#define WSCR (2 * SBUF)

__global__ __launch_bounds__(512, 2) void flash_kernel(
        const ushort* __restrict__ qb,    // [16][2048][64]
        const ushort* __restrict__ kb,    // [16][2048][64] (pre-scaled 0.125*log2e)
        const ushort* __restrict__ vtb,   // [16][64][2048]
        const ushort* __restrict__ ekp,   // [EPAD][64]  (pre-scaled log2e)
        const ushort* __restrict__ evtp,  // [64][EPAD]
        ushort* __restrict__ y) {         // [B,T,C] bf16
    extern __shared__ __align__(16) char dls[];

    int g = blockIdx.x;
    int lbid = ((g & 7) << 5) | (g >> 3);
    int bh = lbid >> 4;
    int pk = lbid & 15;
    int tid = threadIdx.x;
    int w = tid >> 6;
    int sub = w & 3;
    int h = w >> 2;
    int lane = tid & 63;
    int lo = lane & 15, hi = lane >> 4;
    int sw = (lo & 7) << 4;

    char* wbase = dls + WSCR + w * 6144;
    ushort (*Rl)[88]   = (ushort (*)[88])  wbase;
    ushort (*Pl)[72]   = (ushort (*)[72])  wbase;
    ushort (*Ppl)[104] = (ushort (*)[104])(wbase + 2816);

    {
        uint* pz = reinterpret_cast<uint*>(&Ppl[0][0]);
        for (int i = lane; i < 832; i += 64) pz[i] = 0;
    }

    const char* kB  = (const char*)(kb  + (size_t)bh * 2048 * 64);
    const char* vB  = (const char*)(vtb + (size_t)bh * 64 * 2048);
    const char* ekB = (const char*)ekp;
    const char* evB = (const char*)evtp;

    int t0A = (31 - pk) * 64, t0B = pk * 64;
    int NSA = 32 - pk;
    const int NC = 33;

    auto STAGE_KE = [&](int buf, int ci) {    // 3 loads/thread: K + EK band
        int t0 = (ci < NSA) ? t0A : t0B;
        int s0 = ((ci < NSA) ? ci : ci - NSA) * 64;
        int band0 = t0 - s0;
        char* B = dls + buf * SBUF;
        int wb = (tid & 448) << 4;
        {
            int gb = tid * 16;
            int r = gb >> 7, c = gb & 127;
            gload16(kB + (size_t)(s0 + r) * 128 + (c ^ ((r & 7) << 4)), B + KOFF + wb);
        }
#pragma unroll
        for (int p = 0; p < 2; ++p) {
            int gb = p * 8192 + tid * 16;
            int r = gb >> 7, c = gb & 127;
            gload16(ekB + (size_t)(band0 + r) * 128 + (c ^ ((r & 7) << 4)),
                    B + EKOFF + p * 8192 + wb);
        }
    };
    auto STAGE_VE = [&](int buf, int ci) {    // 4 loads/thread: V + EV band
        int t0 = (ci < NSA) ? t0A : t0B;
        int s0 = ((ci < NSA) ? ci : ci - NSA) * 64;
        int band0 = t0 - s0;
        char* B = dls + buf * SBUF;
        int wb = (tid & 448) << 4;
        {
            int gb = tid * 16;
            int r = gb >> 7, c = gb & 127;
            gload16(vB + (size_t)r * 4096 + (size_t)s0 * 2 + (c ^ ((r & 7) << 4)),
                    B + VOFF + wb);
        }
#pragma unroll
        for (int p = 0; p < 3; ++p) {
            int gb = p * 8192 + tid * 16;
            int r = gb / 384, c = gb - r * 384;
            gload16(evB + (size_t)r * 4352 + (size_t)band0 * 2 + (c ^ ((r & 7) << 4)),
                    B + EVOFF + p * 8192 + wb);
        }
    };

    // prologue: Q fragments for both tiles FIRST (oldest in vmcnt order),
    // then chunk 0's stage.
    const ushort* qbaseA = qb + ((size_t)bh * 2048 + t0A + sub * 16) * 64;
    const ushort* qbaseB = qb + ((size_t)bh * 2048 + t0B + sub * 16) * 64;
    bf16x8 qfA0 = *(const bf16x8*)(qbaseA + (size_t)lo * 64 + hi * 8);
    bf16x8 qfA1 = *(const bf16x8*)(qbaseA + (size_t)lo * 64 + 32 + hi * 8);
    bf16x8 qfB0 = *(const bf16x8*)(qbaseB + (size_t)lo * 64 + hi * 8);
    bf16x8 qfB1 = *(const bf16x8*)(qbaseB + (size_t)lo * 64 + 32 + hi * 8);
    STAGE_KE(0, 0);
    STAGE_VE(0, 0);

    int b_ = bh >> 2, h_ = bh & 3;
    int ci = 0;
    int nb = h ? 0 : 2;
    int kcA = h ? 0 : 1, kcB = h ? 1 : 2;

    for (int tile = 0; tile < 2; ++tile) {
        int t0 = tile ? t0B : t0A;
        int NS = tile ? (pk + 1) : NSA;
        bf16x8 qf0 = tile ? qfB0 : qfA0;
        bf16x8 qf1 = tile ? qfB1 : qfA1;

        float rs[4] = {0.0f, 0.0f, 0.0f, 0.0f};
        f32x4 O[4] = {};

        for (int c = 0; c < NS; ++c, ++ci) {
            int cur = ci & 1;
            const char* B = dls + cur * SBUF;
            bool diag = (c == NS - 1);

            // ---- phase A gate: K/EK of cur landed; V/EV still in flight ----
            asm volatile("s_waitcnt vmcnt(4)" ::: "memory");
            __syncthreads();
            if (ci + 1 < NC) STAGE_KE(cur ^ 1, ci + 1);

            // ---- S = Q K^T ----
            f32x4 sacc[2] = {};
            __builtin_amdgcn_s_setprio(1);
#pragma unroll
            for (int ni = 0; ni < 2; ++ni) {
                int R = (2 * h + ni) * 16 + lo;
                bf16x8 b0 = *(const bf16x8*)(B + KOFF + R * 128 + ((hi * 16) ^ sw));
                bf16x8 b1 = *(const bf16x8*)(B + KOFF + R * 128 + ((64 + hi * 16) ^ sw));
                sacc[ni] = MFMA16(qf0, b0, sacc[ni]);
                sacc[ni] = MFMA16(qf1, b1, sacc[ni]);
            }
            // ---- R = Q ek_band^T -> own Rl ----
#pragma unroll
            for (int ni = 0; ni < 3; ++ni) {
                int n = nb + ni;
                int RL = (sub + n) * 16 + lo;
                f32x4 r = {};
                bf16x8 e0 = *(const bf16x8*)(B + EKOFF + RL * 128 + ((hi * 16) ^ sw));
                bf16x8 e1 = *(const bf16x8*)(B + EKOFF + RL * 128 + ((64 + hi * 16) ^ sw));
                r = MFMA16(qf0, e0, r);
                r = MFMA16(qf1, e1, r);
#pragma unroll
                for (int j = 0; j < 4; ++j) Rl[hi * 4 + j][n * 16 + lo] = f2bf(r[j]);
            }
            __builtin_amdgcn_s_setprio(0);
            // ---- combine + mask + exp2 (no staged reads; hides V/EV) ----
            float sv[2][4];
#pragma unroll
            for (int ni = 0; ni < 2; ++ni) {
                int sl = (2 * h + ni) * 16 + lo;
#pragma unroll
                for (int j = 0; j < 4; ++j) {
                    int r_ = hi * 4 + j;
                    sv[ni][j] = sacc[ni][j] + bf2f(Rl[r_][r_ - sl + 64]);
                }
            }
            asm volatile("" ::: "memory");
#pragma unroll
            for (int ni = 0; ni < 2; ++ni) {
                int sl = (2 * h + ni) * 16 + lo;
#pragma unroll
                for (int j = 0; j < 4; ++j) {
                    int r_ = hi * 4 + j;
                    float p = (!diag || sl <= sub * 16 + r_) ? exp2f(sv[ni][j]) : 0.0f;
                    rs[j] += p;
                    ushort pu = f2bf(p);
                    Pl[r_][sl] = pu;
                    Ppl[r_][r_ - sl + 64] = pu;
                }
            }
            asm volatile("" ::: "memory");

            // ---- phase B gate: V/EV of cur landed; next K/EK in flight ----
            if (ci + 1 < NC) asm volatile("s_waitcnt vmcnt(3)" ::: "memory");
            else             asm volatile("s_waitcnt vmcnt(0)" ::: "memory");
            __syncthreads();
            if (ci + 1 < NC) STAGE_VE(cur ^ 1, ci + 1);

            // ---- O += P V + P' embv_band ----
            __builtin_amdgcn_s_setprio(1);
            bf16x8 pa  = *(const bf16x8*)(&Pl[lo][h * 32 + hi * 8]);
            bf16x8 pb0 = *(const bf16x8*)(&Ppl[lo][kcA * 32 + hi * 8]);
            bf16x8 pb1 = *(const bf16x8*)(&Ppl[lo][kcB * 32 + hi * 8]);
#pragma unroll
            for (int n = 0; n < 4; ++n) {
                int R = n * 16 + lo;
                bf16x8 bv = *(const bf16x8*)(B + VOFF + R * 128 + ((h * 64 + hi * 16) ^ sw));
                O[n] = MFMA16(pa, bv, O[n]);
                bf16x8 e0 = *(const bf16x8*)(B + EVOFF + R * 384 +
                                             ((sub * 32 + kcA * 64 + hi * 16) ^ sw));
                O[n] = MFMA16(pb0, e0, O[n]);
                bf16x8 e1 = *(const bf16x8*)(B + EVOFF + R * 384 +
                                             ((sub * 32 + kcB * 64 + hi * 16) ^ sw));
                O[n] = MFMA16(pb1, e1, O[n]);
            }
            __builtin_amdgcn_s_setprio(0);
            asm volatile("" ::: "memory");   // P reads before next chunk's Rl writes
        }

        // ---- pair merge (fixed-point: partials just add) ----
#pragma unroll
        for (int msk = 1; msk < 16; msk <<= 1)
#pragma unroll
            for (int j = 0; j < 4; ++j) rs[j] += __shfl_xor(rs[j], msk);

        // merge scratch = the consumed buffer of the last chunk ((ci-1)&1);
        // in-flight DMA (chunk ci) targets the OTHER buffer.
        char* mscr = dls + ((ci - 1) & 1) * SBUF + sub * 8192;
        __syncthreads();   // all waves done with PV reads of consumed buffer
        if (h == 1) {
            float* Of = (float*)mscr;
#pragma unroll
            for (int n = 0; n < 4; ++n)
#pragma unroll
                for (int j = 0; j < 4; ++j)
                    Of[(hi * 4 + j) * 64 + n * 16 + lo] = O[n][j];
            if (lo == 0)
#pragma unroll
                for (int j = 0; j < 4; ++j)
                    ((float*)(mscr + 4096))[hi * 4 + j] = rs[j];
        }
        __syncthreads();
        if (h == 0) {
            float* Of = (float*)mscr;
            float inv[4];
#pragma unroll
            for (int j = 0; j < 4; ++j)
                inv[j] = 1.0f / (rs[j] + ((float*)(mscr + 4096))[hi * 4 + j]);
#pragma unroll
            for (int n = 0; n < 4; ++n)
#pragma unroll
                for (int j = 0; j < 4; ++j) {
                    int r = t0 + sub * 16 + hi * 4 + j;
                    float v = O[n][j] + Of[(hi * 4 + j) * 64 + n * 16 + lo];
                    y[((size_t)(b_ * 2048 + r)) * 256 + h_ * 64 + n * 16 + lo] =
                        f2bf(v * inv[j]);
                }
        }
        __syncthreads();   // merge reads done before tile B compute overwrites
    }
}

// ---------------------------------------------------------------------------
extern "C" void kernel_launch(void* const* d_in, const int* in_sizes, int n_in,
                              void* d_out, int out_size, void* d_ws, size_t ws_size,
                              hipStream_t stream) {
    const int*   tokens  = (const int*)d_in[0];
    const float* wte     = (const float*)d_in[1];
    const float* ln1_g   = (const float*)d_in[2];
    const float* ln1_b   = (const float*)d_in[3];
    const float* attn_w  = (const float*)d_in[4];
    const float* attn_b  = (const float*)d_in[5];
    const float* proj_w  = (const float*)d_in[6];
    const float* proj_b  = (const float*)d_in[7];
    const float* embk    = (const float*)d_in[8];
    const float* embv    = (const float*)d_in[9];
    const float* ln2_g   = (const float*)d_in[10];
    const float* ln2_b   = (const float*)d_in[11];
    const float* fc_w    = (const float*)d_in[12];
    const float* fc_b    = (const float*)d_in[13];
    const float* mproj_w = (const float*)d_in[14];
    const float* mproj_b = (const float*)d_in[15];
    const float* lnf_g   = (const float*)d_in[16];
    const float* lnf_b   = (const float*)d_in[17];
    const float* head_w  = (const float*)d_in[18];
    float* out = (float*)d_out;

    const int M = BB * TT;  // 8192
    char* wsb = (char*)d_ws;
    float*  x    = (float*)wsb;                               // 8 MB
    ushort* h    = (ushort*)(wsb + ((size_t)8 << 20));        // 4 MB
    ushort* y    = (ushort*)(wsb + ((size_t)12 << 20));       // 4 MB
    ushort* qb   = (ushort*)(wsb + ((size_t)16 << 20));       // 4 MB
    ushort* kbf  = (ushort*)(wsb + ((size_t)20 << 20));       // 4 MB
    ushort* vtb  = (ushort*)(wsb + ((size_t)24 << 20));       // 4 MB
    ushort* ekp  = (ushort*)(wsb + ((size_t)28 << 20));       // 2 x 278528 B
    ushort* evtp = ekp + (size_t)LL * EPAD * 64;              // 2 x 278528 B
    ushort* attn_wb  = (ushort*)(wsb + ((size_t)30 << 20));   // 3.7 MB total
    ushort* proj_wb  = attn_wb + (size_t)LL * 3 * CC * CC;
    ushort* fc_wb    = proj_wb + (size_t)LL * CC * CC;
    ushort* mproj_wb = fc_wb + (size_t)LL * 4 * CC * CC;
    ushort* head_wb  = mproj_wb + (size_t)LL * CC * 4 * CC;
    ushort* fcb = (ushort*)d_out;  // d_out reused as fc scratch (bf16)

    dim3 blk(256);
    const int FLDS = WSCR + 8 * 6144;        // 163840 B
    const int PLDS = 3 * 36864 + 1024;       // 111616 B
    hipFuncSetAttribute(reinterpret_cast<const void*>(flash_kernel),
                        hipFuncAttributeMaxDynamicSharedMemorySize, FLDS);
    hipFuncSetAttribute(reinterpret_cast<const void*>(bgemmln_kernel<4>),
                        hipFuncAttributeMaxDynamicSharedMemorySize, PLDS);
    hipFuncSetAttribute(reinterpret_cast<const void*>(bgemmln_kernel<16>),
                        hipFuncAttributeMaxDynamicSharedMemorySize, PLDS);

    // prep (weights + emb bands) and embed+ln1[0] in ONE launch
    prep_kernel<<<dim3(2880 + M / 4), blk, 0, stream>>>(
        attn_w, proj_w, fc_w, mproj_w, head_w,
        attn_wb, proj_wb, fc_wb, mproj_wb, head_wb,
        embk, embv, ekp, evtp,
        tokens, wte, ln1_g, ln1_b, x, h);

    for (int l = 0; l < LL; l++) {
        bgemmqkv_kernel<<<dim3(12, 64), dim3(512), 0, stream>>>(
            h, attn_wb + (size_t)l * 3 * CC * CC, attn_b + (size_t)l * 3 * CC,
            qb, kbf, vtb);
        flash_kernel<<<dim3(256), dim3(512), FLDS, stream>>>(
            qb, kbf, vtb, ekp + (size_t)l * EPAD * 64, evtp + (size_t)l * 64 * EPAD, y);
        bgemmln_kernel<4><<<dim3(256), dim3(512), PLDS, stream>>>(
            y, proj_wb + (size_t)l * CC * CC, proj_b + (size_t)l * CC,
            x, ln2_g + l * CC, ln2_b + l * CC, h);
        bgemm256_kernel<2><<<dim3(8, 64), dim3(512), 0, stream>>>(
            h, fc_wb + (size_t)l * 4 * CC * CC, fc_b + (size_t)l * 4 * CC,
            nullptr, fcb, 4 * CC, CC);
        const float* ng = (l == 0) ? (ln1_g + CC) : lnf_g;
        const float* nb = (l == 0) ? (ln1_b + CC) : lnf_b;
        bgemmln_kernel<16><<<dim3(256), dim3(512), PLDS, stream>>>(
            fcb, mproj_wb + (size_t)l * CC * 4 * CC, mproj_b + (size_t)l * CC,
            x, ng, nb, h);
    }

    bgemm256_kernel<0><<<dim3(8, 64), dim3(512), 0, stream>>>(
        h, head_wb, nullptr, out, nullptr, VV, CC);
}